// Round 14
// baseline (553.186 us; speedup 1.0000x reference)
//
#include <hip/hip_runtime.h>
#include <hip/hip_fp16.h>
#include <math.h>

#define NN 100000
#define EE 1200000
#define DD 64
#define GG 1024
#define LL 3
#define VOCAB 128
#define SCAN_NB 98     // ceil(100000/1024)
#define PSTR 64        // padded CSR row stride (slots/node); Poisson(12) max-deg << 64
#define FILL_NB 2048   // fill grid: 8 blocks/CU

// ---------------- encoder: h[n][j] = sum_f emb[f][x_atom[n][f]][j] (+ fp16 shadow) ----------------
__global__ __launch_bounds__(256) void enc_kernel(const int* __restrict__ x_atom,
                                                  const float* __restrict__ emb,
                                                  float* __restrict__ h,
                                                  __half* __restrict__ h16) {
    int idx = blockIdx.x * 256 + threadIdx.x;      // n*64 + j
    if (idx >= NN * 64) return;
    int n = idx >> 6, j = idx & 63;
    int v0 = x_atom[n * 3 + 0];
    int v1 = x_atom[n * 3 + 1];
    int v2 = x_atom[n * 3 + 2];
    float v = emb[(0 * VOCAB + v0) * 64 + j]
            + emb[(1 * VOCAB + v1) * 64 + j]
            + emb[(2 * VOCAB + v2) * 64 + j];
    h[idx] = v;
    h16[idx] = __float2half(v);
}

// ---------------- init: hist=0, fill=0 ----------------
__global__ __launch_bounds__(256) void init_kernel(int* __restrict__ hist,
                                                   int* __restrict__ fill) {
    int i = blockIdx.x * 256 + threadIdx.x;
    if (i < NN) { hist[i] = 0; fill[i] = 0; }
}

// ---------------- in-degree histogram (compact fallback path only) ----------------
__global__ __launch_bounds__(256) void hist_kernel(const int* __restrict__ ei,
                                                   int* __restrict__ hist) {
    int e = blockIdx.x * 256 + threadIdx.x;
    if (e >= EE) return;
    atomicAdd(&hist[ei[EE + e]], 1);
}

// ---------------- scan stage 1 (fallback) ----------------
__global__ __launch_bounds__(256) void scan1_kernel(const int* __restrict__ hist,
                                                    int* __restrict__ bsum) {
    __shared__ int sd[256];
    int t = threadIdx.x, b = blockIdx.x;
    int base = b * 1024 + t * 4;
    int s = 0;
#pragma unroll
    for (int u = 0; u < 4; ++u) { int i = base + u; if (i < NN) s += hist[i]; }
    sd[t] = s;
    __syncthreads();
    for (int off = 128; off > 0; off >>= 1) {
        if (t < off) sd[t] += sd[t + off];
        __syncthreads();
    }
    if (t == 0) bsum[b] = sd[0];
}

// ---------------- scan stage 2 (fallback) ----------------
__global__ void scan2_kernel(const int* __restrict__ bsum, int* __restrict__ boff,
                             int* __restrict__ rowst) {
    if (threadIdx.x == 0 && blockIdx.x == 0) {
        int acc = 0;
        for (int i = 0; i < SCAN_NB; ++i) { boff[i] = acc; acc += bsum[i]; }
        rowst[NN] = acc;   // == EE
    }
}

// ---------------- scan stage 3 (fallback) ----------------
__global__ __launch_bounds__(256) void scan3_kernel(const int* __restrict__ hist,
                                                    const int* __restrict__ boff,
                                                    int* __restrict__ rowst) {
    __shared__ int sd[256];
    int t = threadIdx.x, b = blockIdx.x;
    int base = b * 1024 + t * 4;
    int v[4]; int s = 0;
#pragma unroll
    for (int u = 0; u < 4; ++u) {
        int i = base + u;
        v[u] = (i < NN) ? hist[i] : 0;
        s += v[u];
    }
    sd[t] = s;
    __syncthreads();
    for (int off = 1; off < 256; off <<= 1) {
        int a = (t >= off) ? sd[t - off] : 0;
        __syncthreads();
        sd[t] += a;
        __syncthreads();
    }
    int texcl = sd[t] - s;
    int o = boff[b] + texcl;
#pragma unroll
    for (int u = 0; u < 4; ++u) {
        int i = base + u;
        if (i < NN) rowst[i] = o;
        o += v[u];
    }
}

// ---------------- CSR fill: direct 16B pack scatter (known wall ~80us) ----------------
__global__ __launch_bounds__(256) void fill_kernel(const int* __restrict__ ei,
                                                   const float* __restrict__ ea,
                                                   const int* __restrict__ rowst,
                                                   int* __restrict__ fill,
                                                   float4* __restrict__ pack,
                                                   int padded) {
    const int T = FILL_NB * 256;                 // 524288 threads total
    int t0 = blockIdx.x * 256 + threadIdx.x;
    int e[3] = { t0, t0 + T, t0 + 2 * T };
    int d[3]; float4 p[3]; bool v[3];
#pragma unroll
    for (int u = 0; u < 3; ++u) {
        v[u] = (e[u] < EE);
        if (v[u]) {
            int s = ei[e[u]];
            d[u] = ei[EE + e[u]];
            p[u].x = ea[e[u] * 3 + 0];
            p[u].y = ea[e[u] * 3 + 1];
            p[u].z = ea[e[u] * 3 + 2];
            p[u].w = __int_as_float(s);
        }
    }
    int pos[3];
#pragma unroll
    for (int u = 0; u < 3; ++u)
        if (v[u]) pos[u] = atomicAdd(&fill[d[u]], 1);
#pragma unroll
    for (int u = 0; u < 3; ++u) {
        if (v[u]) {
            if (padded) {
                if (pos[u] < PSTR) pack[((size_t)d[u] << 6) + pos[u]] = p[u];
            } else {
                pack[rowst[d[u]] + pos[u]] = p[u];
            }
        }
    }
}

// ---------------- weighted degree: 16-lane group per node, parallel row-sum ----------------
__global__ __launch_bounds__(256) void degdinv_kernel(const float4* __restrict__ pack,
                                                      const int* __restrict__ rowst,
                                                      const int* __restrict__ cnt,
                                                      float* __restrict__ dinv,
                                                      int padded) {
    int n   = (blockIdx.x * 256 + threadIdx.x) >> 4;
    int sub = threadIdx.x & 15;
    if (n >= NN) return;
    int s0 = padded ? (n << 6) : rowst[n];
    int c  = padded ? min(cnt[n], PSTR) : (rowst[n + 1] - rowst[n]);
    float d0 = 0.f, d1 = 0.f, d2 = 0.f;
    for (int s = sub; s < c; s += 16) {
        float4 p = pack[s0 + s];
        d0 += p.x; d1 += p.y; d2 += p.z;
    }
#pragma unroll
    for (int off = 8; off > 0; off >>= 1) {
        d0 += __shfl_down(d0, off, 16);
        d1 += __shfl_down(d1, off, 16);
        d2 += __shfl_down(d2, off, 16);
    }
    if (sub == 0) {
        d0 += 1.0f; d1 += 1.0f; d2 += 1.0f;   // self-loop weight 1
        dinv[n]          = 1.0f / sqrtf(d0);
        dinv[NN + n]     = 1.0f / sqrtf(d1);
        dinv[2 * NN + n] = 1.0f / sqrtf(d2);
    }
}

// ---------------- fold SOURCE-side dinv into pack (dst side applied in agg) ----------------
__global__ __launch_bounds__(256) void normpack_kernel(const float* __restrict__ dinv,
                                                       const int* __restrict__ rowst,
                                                       const int* __restrict__ cnt,
                                                       float4* __restrict__ pack,
                                                       int padded) {
    int n   = (blockIdx.x * 256 + threadIdx.x) >> 4;
    int sub = threadIdx.x & 15;
    if (n >= NN) return;
    int s0 = padded ? (n << 6) : rowst[n];
    int c  = padded ? min(cnt[n], PSTR) : (rowst[n + 1] - rowst[n]);
    for (int s = sub; s < c; s += 16) {
        float4 p = pack[s0 + s];
        int src = __float_as_int(p.w);
        p.x *= dinv[src];
        p.y *= dinv[NN + src];
        p.z *= dinv[2 * NN + src];
        pack[s0 + s] = p;
    }
}

// ---------------- aggregation: masked 8-batches, fp16 gathers, single-select mask,
//                  fp16 agg output (write traffic halved) ----------------
__global__ __launch_bounds__(256) void agg_kernel(const float* __restrict__ h,
                                                  const __half* __restrict__ h16,
                                                  const float4* __restrict__ pack,
                                                  const int* __restrict__ rowst,
                                                  const int* __restrict__ cnt,
                                                  const float* __restrict__ dinv,
                                                  __half* __restrict__ agg16,
                                                  int padded) {
    int n = (blockIdx.x * 256 + threadIdx.x) >> 6;
    int lane = threadIdx.x & 63;
    if (n >= NN) return;
    float d0 = dinv[n], d1 = dinv[NN + n], d2 = dinv[2 * NN + n];
    float hs = h[(size_t)n * 64 + lane];
    float a0 = hs * d0;     // self-loop: src-side factor = dinv_k[n]  (exact fp32)
    float a1 = hs * d1;
    float a2 = hs * d2;
    int s0 = padded ? (n << 6) : rowst[n];
    int s1 = s0 + (padded ? min(cnt[n], PSTR) : (rowst[n + 1] - rowst[n]));
    for (int s = s0; s < s1; s += 8) {
        float4 p[8];
#pragma unroll
        for (int u = 0; u < 8; ++u) {
            int idx = s + u;
            p[u] = pack[(idx < s1) ? idx : s0];
        }
        float hv[8];
#pragma unroll
        for (int u = 0; u < 8; ++u)
            hv[u] = __half2float(h16[(size_t)__float_as_int(p[u].w) * 64 + lane]);
#pragma unroll
        for (int u = 0; u < 8; ++u)
            hv[u] = (s + u < s1) ? hv[u] : 0.f;   // mask ONCE (1 select vs 3 muls)
#pragma unroll
        for (int u = 0; u < 8; ++u) {
            a0 = fmaf(hv[u], p[u].x, a0);
            a1 = fmaf(hv[u], p[u].y, a1);
            a2 = fmaf(hv[u], p[u].z, a2);
        }
    }
    agg16[(size_t)n * 192 + lane]       = __float2half(a0 * d0);
    agg16[(size_t)n * 192 + 64 + lane]  = __float2half(a1 * d1);
    agg16[(size_t)n * 192 + 128 + lane] = __float2half(a2 * d2);
}

// ---------------- GEMM: fp16 agg input, register-prefetch dbuf staging, h16 shadow write ----
__global__ __launch_bounds__(256) void gemm_kernel(const __half* __restrict__ agg16,
                                                   const float* __restrict__ convW,
                                                   const float* __restrict__ convb,
                                                   float* __restrict__ h,
                                                   __half* __restrict__ h16,
                                                   int layer, int dorelu) {
    __shared__ float an[64][68];    // agg chunk [node][k]   (+pad)
    __shared__ float ws[64][64];    // W chunk   [k][col]
    int t = threadIdx.x;
    int n0 = blockIdx.x * 64;
    const float* W = convW + (size_t)layer * 192 * 64;
    const float* B = convb + (size_t)layer * 192;
    int nb = t >> 4, cb = t & 15;
    float acc[4][4] = {{0.f}};

    float fa[16], fw[16];
    // prefetch kc=0
#pragma unroll
    for (int rep = 0; rep < 16; ++rep) {
        int flat = rep * 256 + t;
        int r = flat >> 6, i = flat & 63;
        int n = n0 + r;
        fa[rep] = (n < NN) ? __half2float(agg16[(size_t)n * 192 + i]) : 0.f;
        fw[rep] = W[flat];
    }

    for (int kc = 0; kc < 3; ++kc) {
        __syncthreads();                 // previous compute done reading LDS
#pragma unroll
        for (int rep = 0; rep < 16; ++rep) {
            int flat = rep * 256 + t;
            int r = flat >> 6, i = flat & 63;
            an[r][i] = fa[rep];
            ((float*)ws)[flat] = fw[rep];
        }
        __syncthreads();
        if (kc < 2) {                    // issue next chunk's loads NOW
#pragma unroll
            for (int rep = 0; rep < 16; ++rep) {
                int flat = rep * 256 + t;
                int r = flat >> 6, i = flat & 63;
                int n = n0 + r;
                fa[rep] = (n < NN) ? __half2float(agg16[(size_t)n * 192 + (kc + 1) * 64 + i]) : 0.f;
                fw[rep] = W[(kc + 1) * 4096 + flat];
            }
        }
#pragma unroll 4
        for (int i = 0; i < 64; ++i) {
            float4 wv = *(const float4*)&ws[i][cb * 4];
#pragma unroll
            for (int r = 0; r < 4; ++r) {
                float a = an[nb * 4 + r][i];
                acc[r][0] = fmaf(a, wv.x, acc[r][0]);
                acc[r][1] = fmaf(a, wv.y, acc[r][1]);
                acc[r][2] = fmaf(a, wv.z, acc[r][2]);
                acc[r][3] = fmaf(a, wv.w, acc[r][3]);
            }
        }
    }

    int col0 = cb * 4;
    float bs[4];
#pragma unroll
    for (int c = 0; c < 4; ++c) {
        int col = col0 + c;
        bs[c] = B[col] + B[64 + col] + B[128 + col];
    }
#pragma unroll
    for (int r = 0; r < 4; ++r) {
        int n = n0 + nb * 4 + r;
        if (n < NN) {
            float4 hv = *(const float4*)&h[(size_t)n * 64 + col0];
            float v0 = acc[r][0] + bs[0];
            float v1 = acc[r][1] + bs[1];
            float v2 = acc[r][2] + bs[2];
            float v3 = acc[r][3] + bs[3];
            if (dorelu) {
                v0 = fmaxf(v0, 0.f); v1 = fmaxf(v1, 0.f);
                v2 = fmaxf(v2, 0.f); v3 = fmaxf(v3, 0.f);
            }
            float4 o;
            o.x = v0 + hv.x; o.y = v1 + hv.y; o.z = v2 + hv.z; o.w = v3 + hv.w;
            *(float4*)&h[(size_t)n * 64 + col0] = o;
            union { __half hh[4]; unsigned long long u; } pk;
            pk.hh[0] = __float2half(o.x);
            pk.hh[1] = __float2half(o.y);
            pk.hh[2] = __float2half(o.z);
            pk.hh[3] = __float2half(o.w);
            *(unsigned long long*)&h16[(size_t)n * 64 + col0] = pk.u;
        }
    }
}

// ---------------- graph start offsets via binary search (batch is sorted) ----------------
__global__ __launch_bounds__(256) void gstart_kernel(const int* __restrict__ batch,
                                                     int* __restrict__ gstart) {
    int g = blockIdx.x * 256 + threadIdx.x;
    if (g > GG) return;
    int lo = 0, hi = NN;
    while (lo < hi) {
        int mid = (lo + hi) >> 1;
        if (batch[mid] < g) lo = mid + 1; else hi = mid;
    }
    gstart[g] = lo;
}

// ---------------- mean pool: one block (4 waves) per graph ----------------
__global__ __launch_bounds__(256) void pool_kernel(const float* __restrict__ h,
                                                   const int* __restrict__ gstart,
                                                   float* __restrict__ hg) {
    __shared__ float red[3][64];
    int g = blockIdx.x;
    int w = threadIdx.x >> 6, lane = threadIdx.x & 63;
    int s = gstart[g], e = gstart[g + 1];
    float sum = 0.f;
    for (int n = s + w; n < e; n += 4) sum += h[(size_t)n * 64 + lane];
    if (w) red[w - 1][lane] = sum;
    __syncthreads();
    if (w == 0) {
        sum += red[0][lane] + red[1][lane] + red[2][lane];
        int c = e - s;
        hg[(size_t)g * 64 + lane] = sum / (float)(c > 0 ? c : 1);
    }
}

// ---------------- fc: 3 stacked linears, one wave per graph ----------------
__global__ __launch_bounds__(256) void fc_kernel(const float* __restrict__ hg,
                                                 const float* __restrict__ W1, const float* __restrict__ b1,
                                                 const float* __restrict__ W2, const float* __restrict__ b2,
                                                 const float* __restrict__ W3, const float* __restrict__ b3,
                                                 float* __restrict__ out) {
    int g = (blockIdx.x * 256 + threadIdx.x) >> 6;
    int lane = threadIdx.x & 63;
    if (g >= GG) return;
    float x = hg[(size_t)g * 64 + lane];
    float t1 = b1[lane];
    for (int i = 0; i < 64; ++i) t1 = fmaf(__shfl(x, i, 64), W1[i * 64 + lane], t1);
    float t2 = b2[lane];
    for (int i = 0; i < 64; ++i) t2 = fmaf(__shfl(t1, i, 64), W2[i * 64 + lane], t2);
    float p = t2 * W3[lane];
    for (int off = 32; off > 0; off >>= 1) p += __shfl_down(p, off, 64);
    if (lane == 0) out[g] = p + b3[0];
}

extern "C" void kernel_launch(void* const* d_in, const int* in_sizes, int n_in,
                              void* d_out, int out_size, void* d_ws, size_t ws_size,
                              hipStream_t stream) {
    const int*   x_atom = (const int*)d_in[0];
    const int*   ei     = (const int*)d_in[1];
    const float* ea     = (const float*)d_in[2];
    const int*   batch  = (const int*)d_in[3];
    const float* emb    = (const float*)d_in[4];
    const float* convW  = (const float*)d_in[5];
    const float* convb  = (const float*)d_in[6];
    const float* W1 = (const float*)d_in[7];  const float* b1 = (const float*)d_in[8];
    const float* W2 = (const float*)d_in[9];  const float* b2 = (const float*)d_in[10];
    const float* W3 = (const float*)d_in[11]; const float* b3 = (const float*)d_in[12];
    float* out = (float*)d_out;

    char* p = (char*)d_ws;
    size_t used = 0;
    auto alloc = [&](size_t bytes) -> void* {
        void* r = (void*)p;
        size_t rb = (bytes + 255) & ~(size_t)255;
        p += rb; used += rb;
        return r;
    };
    float*  h     = (float*)alloc((size_t)NN * 64 * 4);       // 25.6 MB
    __half* h16   = (__half*)alloc((size_t)NN * 64 * 2);      // 12.8 MB (gather shadow)
    __half* agg16 = (__half*)alloc((size_t)NN * 192 * 2);     // 38.4 MB (fp16 intermediate)
    float*  dinv  = (float*)alloc((size_t)3 * NN * 4);        // 1.2 MB
    int*    hist  = (int*)alloc((size_t)NN * 4);
    int*    rowst = (int*)alloc((size_t)(NN + 1) * 4);
    int*    fill  = (int*)alloc((size_t)NN * 4);
    int*    bsum  = (int*)alloc(128 * 4);
    int*    boff  = (int*)alloc(128 * 4);
    int*    gstart= (int*)alloc((size_t)(GG + 1) * 4);
    float*  hg    = (float*)alloc((size_t)GG * 64 * 4);
    // pack last: padded (102.4 MB) if workspace allows, else compact (19.2 MB, +8 slot margin)
    size_t padded_pack  = (size_t)NN * PSTR * 16;
    size_t compact_pack = (size_t)(EE + 8) * 16;
    int padded = (ws_size >= used + padded_pack) ? 1 : 0;
    float4* pack = (float4*)alloc(padded ? padded_pack : compact_pack);

    // ---- encoder + CSR build ----
    enc_kernel<<<(NN * 64) / 256, 256, 0, stream>>>(x_atom, emb, h, h16);
    init_kernel<<<(NN + 255) / 256, 256, 0, stream>>>(hist, fill);
    if (!padded) {
        hist_kernel<<<(EE + 255) / 256, 256, 0, stream>>>(ei, hist);
        scan1_kernel<<<SCAN_NB, 256, 0, stream>>>(hist, bsum);
        scan2_kernel<<<1, 64, 0, stream>>>(bsum, boff, rowst);
        scan3_kernel<<<SCAN_NB, 256, 0, stream>>>(hist, boff, rowst);
    }
    fill_kernel<<<FILL_NB, 256, 0, stream>>>(ei, ea, rowst, fill, pack, padded);
    degdinv_kernel<<<(NN * 16 + 255) / 256, 256, 0, stream>>>(pack, rowst, fill, dinv, padded);
    normpack_kernel<<<(NN * 16 + 255) / 256, 256, 0, stream>>>(dinv, rowst, fill, pack, padded);
    gstart_kernel<<<(GG + 1 + 255) / 256, 256, 0, stream>>>(batch, gstart);

    // ---- 3 GCN layers: aggregate-then-GEMM (linearity refactor) ----
    for (int layer = 0; layer < LL; ++layer) {
        agg_kernel<<<NN / 4, 256, 0, stream>>>(h, h16, pack, rowst, fill, dinv, agg16, padded);
        gemm_kernel<<<(NN + 63) / 64, 256, 0, stream>>>(agg16, convW, convb, h, h16, layer,
                                                        (layer < LL - 1) ? 1 : 0);
    }

    // ---- pool + fc ----
    pool_kernel<<<GG, 256, 0, stream>>>(h, gstart, hg);
    fc_kernel<<<GG / 4, 256, 0, stream>>>(hg, W1, b1, W2, b2, W3, b3, out);
}

// Round 15
// 482.424 us; speedup vs baseline: 1.1467x; 1.1467x over previous
//
#include <hip/hip_runtime.h>
#include <hip/hip_fp16.h>
#include <math.h>

#define NN 100000
#define EE 1200000
#define DD 64
#define GG 1024
#define LL 3
#define VOCAB 128
#define SCAN_NB 98     // ceil(100000/1024)
#define PSTR 64        // padded CSR row stride (slots/node); Poisson(12) max-deg << 64
#define FILL_NB 2048   // fill grid: 8 blocks/CU

// ---------------- encoder: h[n][j] = sum_f emb[f][x_atom[n][f]][j] (+ fp16 shadow) ----------------
__global__ __launch_bounds__(256) void enc_kernel(const int* __restrict__ x_atom,
                                                  const float* __restrict__ emb,
                                                  float* __restrict__ h,
                                                  __half* __restrict__ h16) {
    int idx = blockIdx.x * 256 + threadIdx.x;      // n*64 + j
    if (idx >= NN * 64) return;
    int n = idx >> 6, j = idx & 63;
    int v0 = x_atom[n * 3 + 0];
    int v1 = x_atom[n * 3 + 1];
    int v2 = x_atom[n * 3 + 2];
    float v = emb[(0 * VOCAB + v0) * 64 + j]
            + emb[(1 * VOCAB + v1) * 64 + j]
            + emb[(2 * VOCAB + v2) * 64 + j];
    h[idx] = v;
    h16[idx] = __float2half(v);
}

// ---------------- init: hist=0, fill=0 ----------------
__global__ __launch_bounds__(256) void init_kernel(int* __restrict__ hist,
                                                   int* __restrict__ fill) {
    int i = blockIdx.x * 256 + threadIdx.x;
    if (i < NN) { hist[i] = 0; fill[i] = 0; }
}

// ---------------- in-degree histogram (compact fallback path only) ----------------
__global__ __launch_bounds__(256) void hist_kernel(const int* __restrict__ ei,
                                                   int* __restrict__ hist) {
    int e = blockIdx.x * 256 + threadIdx.x;
    if (e >= EE) return;
    atomicAdd(&hist[ei[EE + e]], 1);
}

// ---------------- scan stage 1 (fallback) ----------------
__global__ __launch_bounds__(256) void scan1_kernel(const int* __restrict__ hist,
                                                    int* __restrict__ bsum) {
    __shared__ int sd[256];
    int t = threadIdx.x, b = blockIdx.x;
    int base = b * 1024 + t * 4;
    int s = 0;
#pragma unroll
    for (int u = 0; u < 4; ++u) { int i = base + u; if (i < NN) s += hist[i]; }
    sd[t] = s;
    __syncthreads();
    for (int off = 128; off > 0; off >>= 1) {
        if (t < off) sd[t] += sd[t + off];
        __syncthreads();
    }
    if (t == 0) bsum[b] = sd[0];
}

// ---------------- scan stage 2 (fallback) ----------------
__global__ void scan2_kernel(const int* __restrict__ bsum, int* __restrict__ boff,
                             int* __restrict__ rowst) {
    if (threadIdx.x == 0 && blockIdx.x == 0) {
        int acc = 0;
        for (int i = 0; i < SCAN_NB; ++i) { boff[i] = acc; acc += bsum[i]; }
        rowst[NN] = acc;   // == EE
    }
}

// ---------------- scan stage 3 (fallback) ----------------
__global__ __launch_bounds__(256) void scan3_kernel(const int* __restrict__ hist,
                                                    const int* __restrict__ boff,
                                                    int* __restrict__ rowst) {
    __shared__ int sd[256];
    int t = threadIdx.x, b = blockIdx.x;
    int base = b * 1024 + t * 4;
    int v[4]; int s = 0;
#pragma unroll
    for (int u = 0; u < 4; ++u) {
        int i = base + u;
        v[u] = (i < NN) ? hist[i] : 0;
        s += v[u];
    }
    sd[t] = s;
    __syncthreads();
    for (int off = 1; off < 256; off <<= 1) {
        int a = (t >= off) ? sd[t - off] : 0;
        __syncthreads();
        sd[t] += a;
        __syncthreads();
    }
    int texcl = sd[t] - s;
    int o = boff[b] + texcl;
#pragma unroll
    for (int u = 0; u < 4; ++u) {
        int i = base + u;
        if (i < NN) rowst[i] = o;
        o += v[u];
    }
}

// ---------------- CSR fill: direct 16B pack scatter (known wall ~80us) ----------------
__global__ __launch_bounds__(256) void fill_kernel(const int* __restrict__ ei,
                                                   const float* __restrict__ ea,
                                                   const int* __restrict__ rowst,
                                                   int* __restrict__ fill,
                                                   float4* __restrict__ pack,
                                                   int padded) {
    const int T = FILL_NB * 256;                 // 524288 threads total
    int t0 = blockIdx.x * 256 + threadIdx.x;
    int e[3] = { t0, t0 + T, t0 + 2 * T };
    int d[3]; float4 p[3]; bool v[3];
#pragma unroll
    for (int u = 0; u < 3; ++u) {
        v[u] = (e[u] < EE);
        if (v[u]) {
            int s = ei[e[u]];
            d[u] = ei[EE + e[u]];
            p[u].x = ea[e[u] * 3 + 0];
            p[u].y = ea[e[u] * 3 + 1];
            p[u].z = ea[e[u] * 3 + 2];
            p[u].w = __int_as_float(s);
        }
    }
    int pos[3];
#pragma unroll
    for (int u = 0; u < 3; ++u)
        if (v[u]) pos[u] = atomicAdd(&fill[d[u]], 1);
#pragma unroll
    for (int u = 0; u < 3; ++u) {
        if (v[u]) {
            if (padded) {
                if (pos[u] < PSTR) pack[((size_t)d[u] << 6) + pos[u]] = p[u];
            } else {
                pack[rowst[d[u]] + pos[u]] = p[u];
            }
        }
    }
}

// ---------------- weighted degree: 16-lane group per node, parallel row-sum ----------------
__global__ __launch_bounds__(256) void degdinv_kernel(const float4* __restrict__ pack,
                                                      const int* __restrict__ rowst,
                                                      const int* __restrict__ cnt,
                                                      float* __restrict__ dinv,
                                                      int padded) {
    int n   = (blockIdx.x * 256 + threadIdx.x) >> 4;
    int sub = threadIdx.x & 15;
    if (n >= NN) return;
    int s0 = padded ? (n << 6) : rowst[n];
    int c  = padded ? min(cnt[n], PSTR) : (rowst[n + 1] - rowst[n]);
    float d0 = 0.f, d1 = 0.f, d2 = 0.f;
    for (int s = sub; s < c; s += 16) {
        float4 p = pack[s0 + s];
        d0 += p.x; d1 += p.y; d2 += p.z;
    }
#pragma unroll
    for (int off = 8; off > 0; off >>= 1) {
        d0 += __shfl_down(d0, off, 16);
        d1 += __shfl_down(d1, off, 16);
        d2 += __shfl_down(d2, off, 16);
    }
    if (sub == 0) {
        d0 += 1.0f; d1 += 1.0f; d2 += 1.0f;   // self-loop weight 1
        dinv[n]          = 1.0f / sqrtf(d0);
        dinv[NN + n]     = 1.0f / sqrtf(d1);
        dinv[2 * NN + n] = 1.0f / sqrtf(d2);
    }
}

// ---------------- fold SOURCE-side dinv into pack (dst side applied in agg) ----------------
__global__ __launch_bounds__(256) void normpack_kernel(const float* __restrict__ dinv,
                                                       const int* __restrict__ rowst,
                                                       const int* __restrict__ cnt,
                                                       float4* __restrict__ pack,
                                                       int padded) {
    int n   = (blockIdx.x * 256 + threadIdx.x) >> 4;
    int sub = threadIdx.x & 15;
    if (n >= NN) return;
    int s0 = padded ? (n << 6) : rowst[n];
    int c  = padded ? min(cnt[n], PSTR) : (rowst[n + 1] - rowst[n]);
    for (int s = sub; s < c; s += 16) {
        float4 p = pack[s0 + s];
        int src = __float_as_int(p.w);
        p.x *= dinv[src];
        p.y *= dinv[NN + src];
        p.z *= dinv[2 * NN + src];
        pack[s0 + s] = p;
    }
}

// ---------------- aggregation: masked 8-batches, fp16 gathers, single-select mask,
//                  fp16 agg output ----------------
__global__ __launch_bounds__(256) void agg_kernel(const float* __restrict__ h,
                                                  const __half* __restrict__ h16,
                                                  const float4* __restrict__ pack,
                                                  const int* __restrict__ rowst,
                                                  const int* __restrict__ cnt,
                                                  const float* __restrict__ dinv,
                                                  __half* __restrict__ agg16,
                                                  int padded) {
    int n = (blockIdx.x * 256 + threadIdx.x) >> 6;
    int lane = threadIdx.x & 63;
    if (n >= NN) return;
    float d0 = dinv[n], d1 = dinv[NN + n], d2 = dinv[2 * NN + n];
    float hs = h[(size_t)n * 64 + lane];
    float a0 = hs * d0;     // self-loop: src-side factor = dinv_k[n]  (exact fp32)
    float a1 = hs * d1;
    float a2 = hs * d2;
    int s0 = padded ? (n << 6) : rowst[n];
    int s1 = s0 + (padded ? min(cnt[n], PSTR) : (rowst[n + 1] - rowst[n]));
    for (int s = s0; s < s1; s += 8) {
        float4 p[8];
#pragma unroll
        for (int u = 0; u < 8; ++u) {
            int idx = s + u;
            p[u] = pack[(idx < s1) ? idx : s0];
        }
        float hv[8];
#pragma unroll
        for (int u = 0; u < 8; ++u)
            hv[u] = __half2float(h16[(size_t)__float_as_int(p[u].w) * 64 + lane]);
#pragma unroll
        for (int u = 0; u < 8; ++u)
            hv[u] = (s + u < s1) ? hv[u] : 0.f;   // mask ONCE (1 select vs 3 muls)
#pragma unroll
        for (int u = 0; u < 8; ++u) {
            a0 = fmaf(hv[u], p[u].x, a0);
            a1 = fmaf(hv[u], p[u].y, a1);
            a2 = fmaf(hv[u], p[u].z, a2);
        }
    }
    agg16[(size_t)n * 192 + lane]       = __float2half(a0 * d0);
    agg16[(size_t)n * 192 + 64 + lane]  = __float2half(a1 * d1);
    agg16[(size_t)n * 192 + 128 + lane] = __float2half(a2 * d2);
}

// ---------------- GEMM: fp16 agg input loaded WIDE (uint=2 halves, float4 W),
//                  register-prefetch dbuf staging, h16 shadow write ----------------
__global__ __launch_bounds__(256) void gemm_kernel(const __half* __restrict__ agg16,
                                                   const float* __restrict__ convW,
                                                   const float* __restrict__ convb,
                                                   float* __restrict__ h,
                                                   __half* __restrict__ h16,
                                                   int layer, int dorelu) {
    __shared__ float an[64][68];    // agg chunk [node][k]   (+pad)
    __shared__ float ws[64][64];    // W chunk   [k][col]
    int t = threadIdx.x;
    int n0 = blockIdx.x * 64;
    const float* W = convW + (size_t)layer * 192 * 64;
    const float* B = convb + (size_t)layer * 192;
    int nb = t >> 4, cb = t & 15;
    float acc[4][4] = {{0.f}};

    unsigned int fu[8]; float4 fw[4];
    // prefetch kc=0 (wide: uint = 2 halves, 256B/wave-instr; float4 W = 1KB/instr)
#pragma unroll
    for (int rep = 0; rep < 8; ++rep) {
        int flat = rep * 512 + t * 2;
        int r = flat >> 6, i = flat & 63;
        int n = n0 + r;
        fu[rep] = (n < NN) ? *(const unsigned int*)&agg16[(size_t)n * 192 + i] : 0u;
    }
#pragma unroll
    for (int rep = 0; rep < 4; ++rep)
        fw[rep] = *(const float4*)&W[rep * 1024 + t * 4];

    for (int kc = 0; kc < 3; ++kc) {
        __syncthreads();                 // previous compute done reading LDS
#pragma unroll
        for (int rep = 0; rep < 8; ++rep) {
            int flat = rep * 512 + t * 2;
            int r = flat >> 6, i = flat & 63;
            __half2 hh = *(__half2*)&fu[rep];
            float2 f2 = __half22float2(hh);
            an[r][i]     = f2.x;
            an[r][i + 1] = f2.y;
        }
#pragma unroll
        for (int rep = 0; rep < 4; ++rep)
            *(float4*)&((float*)ws)[rep * 1024 + t * 4] = fw[rep];
        __syncthreads();
        if (kc < 2) {                    // issue next chunk's loads NOW
#pragma unroll
            for (int rep = 0; rep < 8; ++rep) {
                int flat = rep * 512 + t * 2;
                int r = flat >> 6, i = flat & 63;
                int n = n0 + r;
                fu[rep] = (n < NN) ? *(const unsigned int*)&agg16[(size_t)n * 192 + (kc + 1) * 64 + i] : 0u;
            }
#pragma unroll
            for (int rep = 0; rep < 4; ++rep)
                fw[rep] = *(const float4*)&W[(kc + 1) * 4096 + rep * 1024 + t * 4];
        }
#pragma unroll 4
        for (int i = 0; i < 64; ++i) {
            float4 wv = *(const float4*)&ws[i][cb * 4];
#pragma unroll
            for (int r = 0; r < 4; ++r) {
                float a = an[nb * 4 + r][i];
                acc[r][0] = fmaf(a, wv.x, acc[r][0]);
                acc[r][1] = fmaf(a, wv.y, acc[r][1]);
                acc[r][2] = fmaf(a, wv.z, acc[r][2]);
                acc[r][3] = fmaf(a, wv.w, acc[r][3]);
            }
        }
    }

    int col0 = cb * 4;
    float bs[4];
#pragma unroll
    for (int c = 0; c < 4; ++c) {
        int col = col0 + c;
        bs[c] = B[col] + B[64 + col] + B[128 + col];
    }
#pragma unroll
    for (int r = 0; r < 4; ++r) {
        int n = n0 + nb * 4 + r;
        if (n < NN) {
            float4 hv = *(const float4*)&h[(size_t)n * 64 + col0];
            float v0 = acc[r][0] + bs[0];
            float v1 = acc[r][1] + bs[1];
            float v2 = acc[r][2] + bs[2];
            float v3 = acc[r][3] + bs[3];
            if (dorelu) {
                v0 = fmaxf(v0, 0.f); v1 = fmaxf(v1, 0.f);
                v2 = fmaxf(v2, 0.f); v3 = fmaxf(v3, 0.f);
            }
            float4 o;
            o.x = v0 + hv.x; o.y = v1 + hv.y; o.z = v2 + hv.z; o.w = v3 + hv.w;
            *(float4*)&h[(size_t)n * 64 + col0] = o;
            union { __half hh[4]; unsigned long long u; } pk;
            pk.hh[0] = __float2half(o.x);
            pk.hh[1] = __float2half(o.y);
            pk.hh[2] = __float2half(o.z);
            pk.hh[3] = __float2half(o.w);
            *(unsigned long long*)&h16[(size_t)n * 64 + col0] = pk.u;
        }
    }
}

// ---------------- graph start offsets via binary search (batch is sorted) ----------------
__global__ __launch_bounds__(256) void gstart_kernel(const int* __restrict__ batch,
                                                     int* __restrict__ gstart) {
    int g = blockIdx.x * 256 + threadIdx.x;
    if (g > GG) return;
    int lo = 0, hi = NN;
    while (lo < hi) {
        int mid = (lo + hi) >> 1;
        if (batch[mid] < g) lo = mid + 1; else hi = mid;
    }
    gstart[g] = lo;
}

// ---------------- mean pool: one block (4 waves) per graph ----------------
__global__ __launch_bounds__(256) void pool_kernel(const float* __restrict__ h,
                                                   const int* __restrict__ gstart,
                                                   float* __restrict__ hg) {
    __shared__ float red[3][64];
    int g = blockIdx.x;
    int w = threadIdx.x >> 6, lane = threadIdx.x & 63;
    int s = gstart[g], e = gstart[g + 1];
    float sum = 0.f;
    for (int n = s + w; n < e; n += 4) sum += h[(size_t)n * 64 + lane];
    if (w) red[w - 1][lane] = sum;
    __syncthreads();
    if (w == 0) {
        sum += red[0][lane] + red[1][lane] + red[2][lane];
        int c = e - s;
        hg[(size_t)g * 64 + lane] = sum / (float)(c > 0 ? c : 1);
    }
}

// ---------------- fc: 3 stacked linears, one wave per graph ----------------
__global__ __launch_bounds__(256) void fc_kernel(const float* __restrict__ hg,
                                                 const float* __restrict__ W1, const float* __restrict__ b1,
                                                 const float* __restrict__ W2, const float* __restrict__ b2,
                                                 const float* __restrict__ W3, const float* __restrict__ b3,
                                                 float* __restrict__ out) {
    int g = (blockIdx.x * 256 + threadIdx.x) >> 6;
    int lane = threadIdx.x & 63;
    if (g >= GG) return;
    float x = hg[(size_t)g * 64 + lane];
    float t1 = b1[lane];
    for (int i = 0; i < 64; ++i) t1 = fmaf(__shfl(x, i, 64), W1[i * 64 + lane], t1);
    float t2 = b2[lane];
    for (int i = 0; i < 64; ++i) t2 = fmaf(__shfl(t1, i, 64), W2[i * 64 + lane], t2);
    float p = t2 * W3[lane];
    for (int off = 32; off > 0; off >>= 1) p += __shfl_down(p, off, 64);
    if (lane == 0) out[g] = p + b3[0];
}

extern "C" void kernel_launch(void* const* d_in, const int* in_sizes, int n_in,
                              void* d_out, int out_size, void* d_ws, size_t ws_size,
                              hipStream_t stream) {
    const int*   x_atom = (const int*)d_in[0];
    const int*   ei     = (const int*)d_in[1];
    const float* ea     = (const float*)d_in[2];
    const int*   batch  = (const int*)d_in[3];
    const float* emb    = (const float*)d_in[4];
    const float* convW  = (const float*)d_in[5];
    const float* convb  = (const float*)d_in[6];
    const float* W1 = (const float*)d_in[7];  const float* b1 = (const float*)d_in[8];
    const float* W2 = (const float*)d_in[9];  const float* b2 = (const float*)d_in[10];
    const float* W3 = (const float*)d_in[11]; const float* b3 = (const float*)d_in[12];
    float* out = (float*)d_out;

    char* p = (char*)d_ws;
    size_t used = 0;
    auto alloc = [&](size_t bytes) -> void* {
        void* r = (void*)p;
        size_t rb = (bytes + 255) & ~(size_t)255;
        p += rb; used += rb;
        return r;
    };
    float*  h     = (float*)alloc((size_t)NN * 64 * 4);       // 25.6 MB
    __half* h16   = (__half*)alloc((size_t)NN * 64 * 2);      // 12.8 MB (gather shadow)
    __half* agg16 = (__half*)alloc((size_t)NN * 192 * 2);     // 38.4 MB (fp16 intermediate)
    float*  dinv  = (float*)alloc((size_t)3 * NN * 4);        // 1.2 MB
    int*    hist  = (int*)alloc((size_t)NN * 4);
    int*    rowst = (int*)alloc((size_t)(NN + 1) * 4);
    int*    fill  = (int*)alloc((size_t)NN * 4);
    int*    bsum  = (int*)alloc(128 * 4);
    int*    boff  = (int*)alloc(128 * 4);
    int*    gstart= (int*)alloc((size_t)(GG + 1) * 4);
    float*  hg    = (float*)alloc((size_t)GG * 64 * 4);
    // pack last: padded (102.4 MB) if workspace allows, else compact (19.2 MB, +8 slot margin)
    size_t padded_pack  = (size_t)NN * PSTR * 16;
    size_t compact_pack = (size_t)(EE + 8) * 16;
    int padded = (ws_size >= used + padded_pack) ? 1 : 0;
    float4* pack = (float4*)alloc(padded ? padded_pack : compact_pack);

    // ---- encoder + CSR build ----
    enc_kernel<<<(NN * 64) / 256, 256, 0, stream>>>(x_atom, emb, h, h16);
    init_kernel<<<(NN + 255) / 256, 256, 0, stream>>>(hist, fill);
    if (!padded) {
        hist_kernel<<<(EE + 255) / 256, 256, 0, stream>>>(ei, hist);
        scan1_kernel<<<SCAN_NB, 256, 0, stream>>>(hist, bsum);
        scan2_kernel<<<1, 64, 0, stream>>>(bsum, boff, rowst);
        scan3_kernel<<<SCAN_NB, 256, 0, stream>>>(hist, boff, rowst);
    }
    fill_kernel<<<FILL_NB, 256, 0, stream>>>(ei, ea, rowst, fill, pack, padded);
    degdinv_kernel<<<(NN * 16 + 255) / 256, 256, 0, stream>>>(pack, rowst, fill, dinv, padded);
    normpack_kernel<<<(NN * 16 + 255) / 256, 256, 0, stream>>>(dinv, rowst, fill, pack, padded);
    gstart_kernel<<<(GG + 1 + 255) / 256, 256, 0, stream>>>(batch, gstart);

    // ---- 3 GCN layers: aggregate-then-GEMM (linearity refactor) ----
    for (int layer = 0; layer < LL; ++layer) {
        agg_kernel<<<NN / 4, 256, 0, stream>>>(h, h16, pack, rowst, fill, dinv, agg16, padded);
        gemm_kernel<<<(NN + 63) / 64, 256, 0, stream>>>(agg16, convW, convb, h, h16, layer,
                                                        (layer < LL - 1) ? 1 : 0);
    }

    // ---- pool + fc ----
    pool_kernel<<<GG, 256, 0, stream>>>(h, gstart, hg);
    fc_kernel<<<GG / 4, 256, 0, stream>>>(hg, W1, b1, W2, b2, W3, b3, out);
}

// Round 16
// 443.094 us; speedup vs baseline: 1.2485x; 1.0888x over previous
//
#include <hip/hip_runtime.h>
#include <hip/hip_fp16.h>
#include <math.h>

#define NN 100000
#define EE 1200000
#define DD 64
#define GG 1024
#define LL 3
#define VOCAB 128
#define SCAN_NB 98     // ceil(100000/1024)
#define PSTR 64        // padded CSR row stride (slots/node); Poisson(12) max-deg << 64
#define FILL_NB 2048   // fill grid: 8 blocks/CU

// fp16 pair dot with fp32 accumulate; fallback keeps compile safe everywhere
__device__ __forceinline__ float dot2acc(unsigned int a, unsigned int b, float c) {
#if defined(__has_builtin)
#if __has_builtin(__builtin_amdgcn_fdot2)
    typedef _Float16 h2v __attribute__((ext_vector_type(2)));
    union U { unsigned int u; h2v v; };
    U ua, ub; ua.u = a; ub.u = b;
    return __builtin_amdgcn_fdot2(ua.v, ub.v, c, false);
#else
    __half2 ha = *(__half2*)&a, hb = *(__half2*)&b;
    float2 f1 = __half22float2(ha), f2 = __half22float2(hb);
    return fmaf(f1.x, f2.x, fmaf(f1.y, f2.y, c));
#endif
#else
    __half2 ha = *(__half2*)&a, hb = *(__half2*)&b;
    float2 f1 = __half22float2(ha), f2 = __half22float2(hb);
    return fmaf(f1.x, f2.x, fmaf(f1.y, f2.y, c));
#endif
}

// ---------------- encoder: h[n][j] = sum_f emb[f][x_atom[n][f]][j] (+ fp16 shadow) ----------------
__global__ __launch_bounds__(256) void enc_kernel(const int* __restrict__ x_atom,
                                                  const float* __restrict__ emb,
                                                  float* __restrict__ h,
                                                  __half* __restrict__ h16) {
    int idx = blockIdx.x * 256 + threadIdx.x;      // n*64 + j
    if (idx >= NN * 64) return;
    int n = idx >> 6, j = idx & 63;
    int v0 = x_atom[n * 3 + 0];
    int v1 = x_atom[n * 3 + 1];
    int v2 = x_atom[n * 3 + 2];
    float v = emb[(0 * VOCAB + v0) * 64 + j]
            + emb[(1 * VOCAB + v1) * 64 + j]
            + emb[(2 * VOCAB + v2) * 64 + j];
    h[idx] = v;
    h16[idx] = __float2half(v);
}

// ---------------- one-time: pack convW into fp16 k-pairs w16p[layer][96][64] ----------------
__global__ __launch_bounds__(256) void wcvt_kernel(const float* __restrict__ convW,
                                                   unsigned int* __restrict__ w16p) {
    int idx = blockIdx.x * 256 + threadIdx.x;      // layer*96*64 + p*64 + c
    if (idx >= LL * 96 * 64) return;
    int l = idx / (96 * 64);
    int rem = idx - l * 96 * 64;
    int pr = rem >> 6, c = rem & 63;
    const float* W = convW + (size_t)l * 192 * 64;
    __half2 hh = __floats2half2_rn(W[(2 * pr) * 64 + c], W[(2 * pr + 1) * 64 + c]);
    w16p[idx] = *(unsigned int*)&hh;
}

// ---------------- init: hist=0, fill=0 ----------------
__global__ __launch_bounds__(256) void init_kernel(int* __restrict__ hist,
                                                   int* __restrict__ fill) {
    int i = blockIdx.x * 256 + threadIdx.x;
    if (i < NN) { hist[i] = 0; fill[i] = 0; }
}

// ---------------- in-degree histogram (compact fallback path only) ----------------
__global__ __launch_bounds__(256) void hist_kernel(const int* __restrict__ ei,
                                                   int* __restrict__ hist) {
    int e = blockIdx.x * 256 + threadIdx.x;
    if (e >= EE) return;
    atomicAdd(&hist[ei[EE + e]], 1);
}

// ---------------- scan stage 1 (fallback) ----------------
__global__ __launch_bounds__(256) void scan1_kernel(const int* __restrict__ hist,
                                                    int* __restrict__ bsum) {
    __shared__ int sd[256];
    int t = threadIdx.x, b = blockIdx.x;
    int base = b * 1024 + t * 4;
    int s = 0;
#pragma unroll
    for (int u = 0; u < 4; ++u) { int i = base + u; if (i < NN) s += hist[i]; }
    sd[t] = s;
    __syncthreads();
    for (int off = 128; off > 0; off >>= 1) {
        if (t < off) sd[t] += sd[t + off];
        __syncthreads();
    }
    if (t == 0) bsum[b] = sd[0];
}

// ---------------- scan stage 2 (fallback) ----------------
__global__ void scan2_kernel(const int* __restrict__ bsum, int* __restrict__ boff,
                             int* __restrict__ rowst) {
    if (threadIdx.x == 0 && blockIdx.x == 0) {
        int acc = 0;
        for (int i = 0; i < SCAN_NB; ++i) { boff[i] = acc; acc += bsum[i]; }
        rowst[NN] = acc;   // == EE
    }
}

// ---------------- scan stage 3 (fallback) ----------------
__global__ __launch_bounds__(256) void scan3_kernel(const int* __restrict__ hist,
                                                    const int* __restrict__ boff,
                                                    int* __restrict__ rowst) {
    __shared__ int sd[256];
    int t = threadIdx.x, b = blockIdx.x;
    int base = b * 1024 + t * 4;
    int v[4]; int s = 0;
#pragma unroll
    for (int u = 0; u < 4; ++u) {
        int i = base + u;
        v[u] = (i < NN) ? hist[i] : 0;
        s += v[u];
    }
    sd[t] = s;
    __syncthreads();
    for (int off = 1; off < 256; off <<= 1) {
        int a = (t >= off) ? sd[t - off] : 0;
        __syncthreads();
        sd[t] += a;
        __syncthreads();
    }
    int texcl = sd[t] - s;
    int o = boff[b] + texcl;
#pragma unroll
    for (int u = 0; u < 4; ++u) {
        int i = base + u;
        if (i < NN) rowst[i] = o;
        o += v[u];
    }
}

// ---------------- CSR fill: direct 16B pack scatter (known wall ~80us) ----------------
__global__ __launch_bounds__(256) void fill_kernel(const int* __restrict__ ei,
                                                   const float* __restrict__ ea,
                                                   const int* __restrict__ rowst,
                                                   int* __restrict__ fill,
                                                   float4* __restrict__ pack,
                                                   int padded) {
    const int T = FILL_NB * 256;                 // 524288 threads total
    int t0 = blockIdx.x * 256 + threadIdx.x;
    int e[3] = { t0, t0 + T, t0 + 2 * T };
    int d[3]; float4 p[3]; bool v[3];
#pragma unroll
    for (int u = 0; u < 3; ++u) {
        v[u] = (e[u] < EE);
        if (v[u]) {
            int s = ei[e[u]];
            d[u] = ei[EE + e[u]];
            p[u].x = ea[e[u] * 3 + 0];
            p[u].y = ea[e[u] * 3 + 1];
            p[u].z = ea[e[u] * 3 + 2];
            p[u].w = __int_as_float(s);
        }
    }
    int pos[3];
#pragma unroll
    for (int u = 0; u < 3; ++u)
        if (v[u]) pos[u] = atomicAdd(&fill[d[u]], 1);
#pragma unroll
    for (int u = 0; u < 3; ++u) {
        if (v[u]) {
            if (padded) {
                if (pos[u] < PSTR) pack[((size_t)d[u] << 6) + pos[u]] = p[u];
            } else {
                pack[rowst[d[u]] + pos[u]] = p[u];
            }
        }
    }
}

// ---------------- weighted degree: 16-lane group per node, parallel row-sum ----------------
__global__ __launch_bounds__(256) void degdinv_kernel(const float4* __restrict__ pack,
                                                      const int* __restrict__ rowst,
                                                      const int* __restrict__ cnt,
                                                      float* __restrict__ dinv,
                                                      int padded) {
    int n   = (blockIdx.x * 256 + threadIdx.x) >> 4;
    int sub = threadIdx.x & 15;
    if (n >= NN) return;
    int s0 = padded ? (n << 6) : rowst[n];
    int c  = padded ? min(cnt[n], PSTR) : (rowst[n + 1] - rowst[n]);
    float d0 = 0.f, d1 = 0.f, d2 = 0.f;
    for (int s = sub; s < c; s += 16) {
        float4 p = pack[s0 + s];
        d0 += p.x; d1 += p.y; d2 += p.z;
    }
#pragma unroll
    for (int off = 8; off > 0; off >>= 1) {
        d0 += __shfl_down(d0, off, 16);
        d1 += __shfl_down(d1, off, 16);
        d2 += __shfl_down(d2, off, 16);
    }
    if (sub == 0) {
        d0 += 1.0f; d1 += 1.0f; d2 += 1.0f;   // self-loop weight 1
        dinv[n]          = 1.0f / sqrtf(d0);
        dinv[NN + n]     = 1.0f / sqrtf(d1);
        dinv[2 * NN + n] = 1.0f / sqrtf(d2);
    }
}

// ---------------- fold SOURCE-side dinv into pack (dst side applied in agg) ----------------
__global__ __launch_bounds__(256) void normpack_kernel(const float* __restrict__ dinv,
                                                       const int* __restrict__ rowst,
                                                       const int* __restrict__ cnt,
                                                       float4* __restrict__ pack,
                                                       int padded) {
    int n   = (blockIdx.x * 256 + threadIdx.x) >> 4;
    int sub = threadIdx.x & 15;
    if (n >= NN) return;
    int s0 = padded ? (n << 6) : rowst[n];
    int c  = padded ? min(cnt[n], PSTR) : (rowst[n + 1] - rowst[n]);
    for (int s = sub; s < c; s += 16) {
        float4 p = pack[s0 + s];
        int src = __float_as_int(p.w);
        p.x *= dinv[src];
        p.y *= dinv[NN + src];
        p.z *= dinv[2 * NN + src];
        pack[s0 + s] = p;
    }
}

// ---------------- aggregation: masked 8-batches, fp16 gathers, single-select mask,
//                  fp16 agg output ----------------
__global__ __launch_bounds__(256) void agg_kernel(const float* __restrict__ h,
                                                  const __half* __restrict__ h16,
                                                  const float4* __restrict__ pack,
                                                  const int* __restrict__ rowst,
                                                  const int* __restrict__ cnt,
                                                  const float* __restrict__ dinv,
                                                  __half* __restrict__ agg16,
                                                  int padded) {
    int n = (blockIdx.x * 256 + threadIdx.x) >> 6;
    int lane = threadIdx.x & 63;
    if (n >= NN) return;
    float d0 = dinv[n], d1 = dinv[NN + n], d2 = dinv[2 * NN + n];
    float hs = h[(size_t)n * 64 + lane];
    float a0 = hs * d0;     // self-loop: src-side factor = dinv_k[n]  (exact fp32)
    float a1 = hs * d1;
    float a2 = hs * d2;
    int s0 = padded ? (n << 6) : rowst[n];
    int s1 = s0 + (padded ? min(cnt[n], PSTR) : (rowst[n + 1] - rowst[n]));
    for (int s = s0; s < s1; s += 8) {
        float4 p[8];
#pragma unroll
        for (int u = 0; u < 8; ++u) {
            int idx = s + u;
            p[u] = pack[(idx < s1) ? idx : s0];
        }
        float hv[8];
#pragma unroll
        for (int u = 0; u < 8; ++u)
            hv[u] = __half2float(h16[(size_t)__float_as_int(p[u].w) * 64 + lane]);
#pragma unroll
        for (int u = 0; u < 8; ++u)
            hv[u] = (s + u < s1) ? hv[u] : 0.f;   // mask ONCE (1 select vs 3 muls)
#pragma unroll
        for (int u = 0; u < 8; ++u) {
            a0 = fmaf(hv[u], p[u].x, a0);
            a1 = fmaf(hv[u], p[u].y, a1);
            a2 = fmaf(hv[u], p[u].z, a2);
        }
    }
    agg16[(size_t)n * 192 + lane]       = __float2half(a0 * d0);
    agg16[(size_t)n * 192 + 64 + lane]  = __float2half(a1 * d1);
    agg16[(size_t)n * 192 + 128 + lane] = __float2half(a2 * d2);
}

// ---------------- GEMM v3: fp16-pair LDS tiles + v_dot2_f32_f16 inner loop ----------------
// anp[kk][r] = half2(agg[r][2kk],agg[r][2kk+1]); wp[kk][c] = half2(W[2kk][c],W[2kk+1][c])
// per kk: 2x ds_read_b128 + 16 dot2 per thread. LDS 17.4KB -> 8 blocks/CU.
__global__ __launch_bounds__(256) void gemm_kernel(const __half* __restrict__ agg16,
                                                   const unsigned int* __restrict__ w16p,
                                                   const float* __restrict__ convb,
                                                   float* __restrict__ h,
                                                   __half* __restrict__ h16,
                                                   int layer, int dorelu) {
    __shared__ unsigned int anp[32 * 68];   // [kk][r] pad 68
    __shared__ unsigned int wp[32 * 68];    // [kk][c] pad 68
    int t = threadIdx.x;
    int n0 = blockIdx.x * 64;
    const unsigned int* Wp = w16p + (size_t)layer * 96 * 64;
    const float* B = convb + (size_t)layer * 192;
    int nb = t >> 4, cb = t & 15;
    float acc[4][4] = {{0.f}};

    unsigned int fa[8], fw[8];
    // prefetch kc=0: agg pairs (coalesced row-major), W pairs (preconverted)
#pragma unroll
    for (int rep = 0; rep < 8; ++rep) {
        int flat = rep * 256 + t;
        int r = flat >> 5, kk = flat & 31;
        int n = n0 + r;
        fa[rep] = (n < NN) ? *(const unsigned int*)&agg16[(size_t)n * 192 + kk * 2] : 0u;
        int kg = flat >> 6, c = flat & 63;
        fw[rep] = Wp[(size_t)kg * 64 + c];
    }

    for (int kc = 0; kc < 3; ++kc) {
        __syncthreads();                 // previous compute done reading LDS
#pragma unroll
        for (int rep = 0; rep < 8; ++rep) {
            int flat = rep * 256 + t;
            int r = flat >> 5, kk = flat & 31;
            anp[kk * 68 + r] = fa[rep];            // transposed store
            int kg = flat >> 6, c = flat & 63;
            wp[(kg & 31) * 68 + c + (kg >> 5) * 0] = fw[rep];  // kg<32 always per chunk
        }
        __syncthreads();
        if (kc < 2) {                    // issue next chunk's loads NOW
#pragma unroll
            for (int rep = 0; rep < 8; ++rep) {
                int flat = rep * 256 + t;
                int r = flat >> 5, kk = flat & 31;
                int n = n0 + r;
                fa[rep] = (n < NN) ? *(const unsigned int*)&agg16[(size_t)n * 192 + (kc + 1) * 64 + kk * 2] : 0u;
                int kg = flat >> 6, c = flat & 63;
                fw[rep] = Wp[((size_t)(kc + 1) * 32 + kg) * 64 + c];
            }
        }
#pragma unroll 8
        for (int kk = 0; kk < 32; ++kk) {
            uint4 av = *(const uint4*)&anp[kk * 68 + nb * 4];
            uint4 wv = *(const uint4*)&wp[kk * 68 + cb * 4];
            const unsigned int avr[4] = { av.x, av.y, av.z, av.w };
            const unsigned int wvc[4] = { wv.x, wv.y, wv.z, wv.w };
#pragma unroll
            for (int r = 0; r < 4; ++r) {
#pragma unroll
                for (int c = 0; c < 4; ++c)
                    acc[r][c] = dot2acc(avr[r], wvc[c], acc[r][c]);
            }
        }
    }

    int col0 = cb * 4;
    float bs[4];
#pragma unroll
    for (int c = 0; c < 4; ++c) {
        int col = col0 + c;
        bs[c] = B[col] + B[64 + col] + B[128 + col];
    }
#pragma unroll
    for (int r = 0; r < 4; ++r) {
        int n = n0 + nb * 4 + r;
        if (n < NN) {
            float4 hv = *(const float4*)&h[(size_t)n * 64 + col0];
            float v0 = acc[r][0] + bs[0];
            float v1 = acc[r][1] + bs[1];
            float v2 = acc[r][2] + bs[2];
            float v3 = acc[r][3] + bs[3];
            if (dorelu) {
                v0 = fmaxf(v0, 0.f); v1 = fmaxf(v1, 0.f);
                v2 = fmaxf(v2, 0.f); v3 = fmaxf(v3, 0.f);
            }
            float4 o;
            o.x = v0 + hv.x; o.y = v1 + hv.y; o.z = v2 + hv.z; o.w = v3 + hv.w;
            *(float4*)&h[(size_t)n * 64 + col0] = o;
            union { __half hh[4]; unsigned long long u; } pk;
            pk.hh[0] = __float2half(o.x);
            pk.hh[1] = __float2half(o.y);
            pk.hh[2] = __float2half(o.z);
            pk.hh[3] = __float2half(o.w);
            *(unsigned long long*)&h16[(size_t)n * 64 + col0] = pk.u;
        }
    }
}

// ---------------- graph start offsets via binary search (batch is sorted) ----------------
__global__ __launch_bounds__(256) void gstart_kernel(const int* __restrict__ batch,
                                                     int* __restrict__ gstart) {
    int g = blockIdx.x * 256 + threadIdx.x;
    if (g > GG) return;
    int lo = 0, hi = NN;
    while (lo < hi) {
        int mid = (lo + hi) >> 1;
        if (batch[mid] < g) lo = mid + 1; else hi = mid;
    }
    gstart[g] = lo;
}

// ---------------- mean pool: one block (4 waves) per graph ----------------
__global__ __launch_bounds__(256) void pool_kernel(const float* __restrict__ h,
                                                   const int* __restrict__ gstart,
                                                   float* __restrict__ hg) {
    __shared__ float red[3][64];
    int g = blockIdx.x;
    int w = threadIdx.x >> 6, lane = threadIdx.x & 63;
    int s = gstart[g], e = gstart[g + 1];
    float sum = 0.f;
    for (int n = s + w; n < e; n += 4) sum += h[(size_t)n * 64 + lane];
    if (w) red[w - 1][lane] = sum;
    __syncthreads();
    if (w == 0) {
        sum += red[0][lane] + red[1][lane] + red[2][lane];
        int c = e - s;
        hg[(size_t)g * 64 + lane] = sum / (float)(c > 0 ? c : 1);
    }
}

// ---------------- fc: 3 stacked linears, one wave per graph ----------------
__global__ __launch_bounds__(256) void fc_kernel(const float* __restrict__ hg,
                                                 const float* __restrict__ W1, const float* __restrict__ b1,
                                                 const float* __restrict__ W2, const float* __restrict__ b2,
                                                 const float* __restrict__ W3, const float* __restrict__ b3,
                                                 float* __restrict__ out) {
    int g = (blockIdx.x * 256 + threadIdx.x) >> 6;
    int lane = threadIdx.x & 63;
    if (g >= GG) return;
    float x = hg[(size_t)g * 64 + lane];
    float t1 = b1[lane];
    for (int i = 0; i < 64; ++i) t1 = fmaf(__shfl(x, i, 64), W1[i * 64 + lane], t1);
    float t2 = b2[lane];
    for (int i = 0; i < 64; ++i) t2 = fmaf(__shfl(t1, i, 64), W2[i * 64 + lane], t2);
    float p = t2 * W3[lane];
    for (int off = 32; off > 0; off >>= 1) p += __shfl_down(p, off, 64);
    if (lane == 0) out[g] = p + b3[0];
}

extern "C" void kernel_launch(void* const* d_in, const int* in_sizes, int n_in,
                              void* d_out, int out_size, void* d_ws, size_t ws_size,
                              hipStream_t stream) {
    const int*   x_atom = (const int*)d_in[0];
    const int*   ei     = (const int*)d_in[1];
    const float* ea     = (const float*)d_in[2];
    const int*   batch  = (const int*)d_in[3];
    const float* emb    = (const float*)d_in[4];
    const float* convW  = (const float*)d_in[5];
    const float* convb  = (const float*)d_in[6];
    const float* W1 = (const float*)d_in[7];  const float* b1 = (const float*)d_in[8];
    const float* W2 = (const float*)d_in[9];  const float* b2 = (const float*)d_in[10];
    const float* W3 = (const float*)d_in[11]; const float* b3 = (const float*)d_in[12];
    float* out = (float*)d_out;

    char* p = (char*)d_ws;
    size_t used = 0;
    auto alloc = [&](size_t bytes) -> void* {
        void* r = (void*)p;
        size_t rb = (bytes + 255) & ~(size_t)255;
        p += rb; used += rb;
        return r;
    };
    float*  h     = (float*)alloc((size_t)NN * 64 * 4);       // 25.6 MB
    __half* h16   = (__half*)alloc((size_t)NN * 64 * 2);      // 12.8 MB (gather shadow)
    __half* agg16 = (__half*)alloc((size_t)NN * 192 * 2);     // 38.4 MB (fp16 intermediate)
    unsigned int* w16p = (unsigned int*)alloc((size_t)LL * 96 * 64 * 4);  // 74KB fp16 W pairs
    float*  dinv  = (float*)alloc((size_t)3 * NN * 4);        // 1.2 MB
    int*    hist  = (int*)alloc((size_t)NN * 4);
    int*    rowst = (int*)alloc((size_t)(NN + 1) * 4);
    int*    fill  = (int*)alloc((size_t)NN * 4);
    int*    bsum  = (int*)alloc(128 * 4);
    int*    boff  = (int*)alloc(128 * 4);
    int*    gstart= (int*)alloc((size_t)(GG + 1) * 4);
    float*  hg    = (float*)alloc((size_t)GG * 64 * 4);
    // pack last: padded (102.4 MB) if workspace allows, else compact (19.2 MB, +8 slot margin)
    size_t padded_pack  = (size_t)NN * PSTR * 16;
    size_t compact_pack = (size_t)(EE + 8) * 16;
    int padded = (ws_size >= used + padded_pack) ? 1 : 0;
    float4* pack = (float4*)alloc(padded ? padded_pack : compact_pack);

    // ---- encoder + W conversion + CSR build ----
    enc_kernel<<<(NN * 64) / 256, 256, 0, stream>>>(x_atom, emb, h, h16);
    wcvt_kernel<<<(LL * 96 * 64 + 255) / 256, 256, 0, stream>>>(convW, w16p);
    init_kernel<<<(NN + 255) / 256, 256, 0, stream>>>(hist, fill);
    if (!padded) {
        hist_kernel<<<(EE + 255) / 256, 256, 0, stream>>>(ei, hist);
        scan1_kernel<<<SCAN_NB, 256, 0, stream>>>(hist, bsum);
        scan2_kernel<<<1, 64, 0, stream>>>(bsum, boff, rowst);
        scan3_kernel<<<SCAN_NB, 256, 0, stream>>>(hist, boff, rowst);
    }
    fill_kernel<<<FILL_NB, 256, 0, stream>>>(ei, ea, rowst, fill, pack, padded);
    degdinv_kernel<<<(NN * 16 + 255) / 256, 256, 0, stream>>>(pack, rowst, fill, dinv, padded);
    normpack_kernel<<<(NN * 16 + 255) / 256, 256, 0, stream>>>(dinv, rowst, fill, pack, padded);
    gstart_kernel<<<(GG + 1 + 255) / 256, 256, 0, stream>>>(batch, gstart);

    // ---- 3 GCN layers: aggregate-then-GEMM (linearity refactor) ----
    for (int layer = 0; layer < LL; ++layer) {
        agg_kernel<<<NN / 4, 256, 0, stream>>>(h, h16, pack, rowst, fill, dinv, agg16, padded);
        gemm_kernel<<<(NN + 63) / 64, 256, 0, stream>>>(agg16, w16p, convb, h, h16, layer,
                                                        (layer < LL - 1) ? 1 : 0);
    }

    // ---- pool + fc ----
    pool_kernel<<<GG, 256, 0, stream>>>(h, gstart, hg);
    fc_kernel<<<GG / 4, 256, 0, stream>>>(hg, W1, b1, W2, b2, W3, b3, out);
}

// Round 17
// 442.109 us; speedup vs baseline: 1.2512x; 1.0022x over previous
//
#include <hip/hip_runtime.h>
#include <hip/hip_fp16.h>
#include <math.h>

#define NN 100000
#define EE 1200000
#define DD 64
#define GG 1024
#define LL 3
#define VOCAB 128
#define SCAN_NB 98     // ceil(100000/1024)
#define PSTR 64        // padded CSR row stride (slots/node); Poisson(12) max-deg << 64
#define FILL_NB 2048   // fill grid: 8 blocks/CU

// fp16 pair dot with fp32 accumulate; fallback keeps compile safe everywhere
__device__ __forceinline__ float dot2acc(unsigned int a, unsigned int b, float c) {
#if defined(__has_builtin)
#if __has_builtin(__builtin_amdgcn_fdot2)
    typedef _Float16 h2v __attribute__((ext_vector_type(2)));
    union U { unsigned int u; h2v v; };
    U ua, ub; ua.u = a; ub.u = b;
    return __builtin_amdgcn_fdot2(ua.v, ub.v, c, false);
#else
    __half2 ha = *(__half2*)&a, hb = *(__half2*)&b;
    float2 f1 = __half22float2(ha), f2 = __half22float2(hb);
    return fmaf(f1.x, f2.x, fmaf(f1.y, f2.y, c));
#endif
#else
    __half2 ha = *(__half2*)&a, hb = *(__half2*)&b;
    float2 f1 = __half22float2(ha), f2 = __half22float2(hb);
    return fmaf(f1.x, f2.x, fmaf(f1.y, f2.y, c));
#endif
}

// ---------------- encoder: h[n][j] = sum_f emb[f][x_atom[n][f]][j] (+ fp16 shadow) ----------------
__global__ __launch_bounds__(256) void enc_kernel(const int* __restrict__ x_atom,
                                                  const float* __restrict__ emb,
                                                  float* __restrict__ h,
                                                  __half* __restrict__ h16) {
    int idx = blockIdx.x * 256 + threadIdx.x;      // n*64 + j
    if (idx >= NN * 64) return;
    int n = idx >> 6, j = idx & 63;
    int v0 = x_atom[n * 3 + 0];
    int v1 = x_atom[n * 3 + 1];
    int v2 = x_atom[n * 3 + 2];
    float v = emb[(0 * VOCAB + v0) * 64 + j]
            + emb[(1 * VOCAB + v1) * 64 + j]
            + emb[(2 * VOCAB + v2) * 64 + j];
    h[idx] = v;
    h16[idx] = __float2half(v);
}

// ---------------- one-time: pack convW into fp16 k-pairs w16p[layer][96][64] ----------------
__global__ __launch_bounds__(256) void wcvt_kernel(const float* __restrict__ convW,
                                                   unsigned int* __restrict__ w16p) {
    int idx = blockIdx.x * 256 + threadIdx.x;      // layer*96*64 + p*64 + c
    if (idx >= LL * 96 * 64) return;
    int l = idx / (96 * 64);
    int rem = idx - l * 96 * 64;
    int pr = rem >> 6, c = rem & 63;
    const float* W = convW + (size_t)l * 192 * 64;
    __half2 hh = __floats2half2_rn(W[(2 * pr) * 64 + c], W[(2 * pr + 1) * 64 + c]);
    w16p[idx] = *(unsigned int*)&hh;
}

// ---------------- init: hist=0, fill=0 ----------------
__global__ __launch_bounds__(256) void init_kernel(int* __restrict__ hist,
                                                   int* __restrict__ fill) {
    int i = blockIdx.x * 256 + threadIdx.x;
    if (i < NN) { hist[i] = 0; fill[i] = 0; }
}

// ---------------- in-degree histogram (compact fallback path only) ----------------
__global__ __launch_bounds__(256) void hist_kernel(const int* __restrict__ ei,
                                                   int* __restrict__ hist) {
    int e = blockIdx.x * 256 + threadIdx.x;
    if (e >= EE) return;
    atomicAdd(&hist[ei[EE + e]], 1);
}

// ---------------- scan stage 1 (fallback) ----------------
__global__ __launch_bounds__(256) void scan1_kernel(const int* __restrict__ hist,
                                                    int* __restrict__ bsum) {
    __shared__ int sd[256];
    int t = threadIdx.x, b = blockIdx.x;
    int base = b * 1024 + t * 4;
    int s = 0;
#pragma unroll
    for (int u = 0; u < 4; ++u) { int i = base + u; if (i < NN) s += hist[i]; }
    sd[t] = s;
    __syncthreads();
    for (int off = 128; off > 0; off >>= 1) {
        if (t < off) sd[t] += sd[t + off];
        __syncthreads();
    }
    if (t == 0) bsum[b] = sd[0];
}

// ---------------- scan stage 2 (fallback) ----------------
__global__ void scan2_kernel(const int* __restrict__ bsum, int* __restrict__ boff,
                             int* __restrict__ rowst) {
    if (threadIdx.x == 0 && blockIdx.x == 0) {
        int acc = 0;
        for (int i = 0; i < SCAN_NB; ++i) { boff[i] = acc; acc += bsum[i]; }
        rowst[NN] = acc;   // == EE
    }
}

// ---------------- scan stage 3 (fallback) ----------------
__global__ __launch_bounds__(256) void scan3_kernel(const int* __restrict__ hist,
                                                    const int* __restrict__ boff,
                                                    int* __restrict__ rowst) {
    __shared__ int sd[256];
    int t = threadIdx.x, b = blockIdx.x;
    int base = b * 1024 + t * 4;
    int v[4]; int s = 0;
#pragma unroll
    for (int u = 0; u < 4; ++u) {
        int i = base + u;
        v[u] = (i < NN) ? hist[i] : 0;
        s += v[u];
    }
    sd[t] = s;
    __syncthreads();
    for (int off = 1; off < 256; off <<= 1) {
        int a = (t >= off) ? sd[t - off] : 0;
        __syncthreads();
        sd[t] += a;
        __syncthreads();
    }
    int texcl = sd[t] - s;
    int o = boff[b] + texcl;
#pragma unroll
    for (int u = 0; u < 4; ++u) {
        int i = base + u;
        if (i < NN) rowst[i] = o;
        o += v[u];
    }
}

// ---------------- CSR fill: direct 16B pack scatter (known wall ~80us) ----------------
__global__ __launch_bounds__(256) void fill_kernel(const int* __restrict__ ei,
                                                   const float* __restrict__ ea,
                                                   const int* __restrict__ rowst,
                                                   int* __restrict__ fill,
                                                   float4* __restrict__ pack,
                                                   int padded) {
    const int T = FILL_NB * 256;                 // 524288 threads total
    int t0 = blockIdx.x * 256 + threadIdx.x;
    int e[3] = { t0, t0 + T, t0 + 2 * T };
    int d[3]; float4 p[3]; bool v[3];
#pragma unroll
    for (int u = 0; u < 3; ++u) {
        v[u] = (e[u] < EE);
        if (v[u]) {
            int s = ei[e[u]];
            d[u] = ei[EE + e[u]];
            p[u].x = ea[e[u] * 3 + 0];
            p[u].y = ea[e[u] * 3 + 1];
            p[u].z = ea[e[u] * 3 + 2];
            p[u].w = __int_as_float(s);
        }
    }
    int pos[3];
#pragma unroll
    for (int u = 0; u < 3; ++u)
        if (v[u]) pos[u] = atomicAdd(&fill[d[u]], 1);
#pragma unroll
    for (int u = 0; u < 3; ++u) {
        if (v[u]) {
            if (padded) {
                if (pos[u] < PSTR) pack[((size_t)d[u] << 6) + pos[u]] = p[u];
            } else {
                pack[rowst[d[u]] + pos[u]] = p[u];
            }
        }
    }
}

// ---------------- weighted degree: 16-lane group per node, parallel row-sum ----------------
__global__ __launch_bounds__(256) void degdinv_kernel(const float4* __restrict__ pack,
                                                      const int* __restrict__ rowst,
                                                      const int* __restrict__ cnt,
                                                      float* __restrict__ dinv,
                                                      int padded) {
    int n   = (blockIdx.x * 256 + threadIdx.x) >> 4;
    int sub = threadIdx.x & 15;
    if (n >= NN) return;
    int s0 = padded ? (n << 6) : rowst[n];
    int c  = padded ? min(cnt[n], PSTR) : (rowst[n + 1] - rowst[n]);
    float d0 = 0.f, d1 = 0.f, d2 = 0.f;
    for (int s = sub; s < c; s += 16) {
        float4 p = pack[s0 + s];
        d0 += p.x; d1 += p.y; d2 += p.z;
    }
#pragma unroll
    for (int off = 8; off > 0; off >>= 1) {
        d0 += __shfl_down(d0, off, 16);
        d1 += __shfl_down(d1, off, 16);
        d2 += __shfl_down(d2, off, 16);
    }
    if (sub == 0) {
        d0 += 1.0f; d1 += 1.0f; d2 += 1.0f;   // self-loop weight 1
        dinv[n]          = 1.0f / sqrtf(d0);
        dinv[NN + n]     = 1.0f / sqrtf(d1);
        dinv[2 * NN + n] = 1.0f / sqrtf(d2);
    }
}

// ---------------- fold SOURCE-side dinv into pack (dst side applied in agg) ----------------
__global__ __launch_bounds__(256) void normpack_kernel(const float* __restrict__ dinv,
                                                       const int* __restrict__ rowst,
                                                       const int* __restrict__ cnt,
                                                       float4* __restrict__ pack,
                                                       int padded) {
    int n   = (blockIdx.x * 256 + threadIdx.x) >> 4;
    int sub = threadIdx.x & 15;
    if (n >= NN) return;
    int s0 = padded ? (n << 6) : rowst[n];
    int c  = padded ? min(cnt[n], PSTR) : (rowst[n + 1] - rowst[n]);
    for (int s = sub; s < c; s += 16) {
        float4 p = pack[s0 + s];
        int src = __float_as_int(p.w);
        p.x *= dinv[src];
        p.y *= dinv[NN + src];
        p.z *= dinv[2 * NN + src];
        pack[s0 + s] = p;
    }
}

// ---------------- aggregation: masked 8-batches, ALL rows from fp16 shadow (no fp32 h read),
//                  single-select mask, fp16 agg output ----------------
__global__ __launch_bounds__(256) void agg_kernel(const __half* __restrict__ h16,
                                                  const float4* __restrict__ pack,
                                                  const int* __restrict__ rowst,
                                                  const int* __restrict__ cnt,
                                                  const float* __restrict__ dinv,
                                                  __half* __restrict__ agg16,
                                                  int padded) {
    int n = (blockIdx.x * 256 + threadIdx.x) >> 6;
    int lane = threadIdx.x & 63;
    if (n >= NN) return;
    float d0 = dinv[n], d1 = dinv[NN + n], d2 = dinv[2 * NN + n];
    float hs = __half2float(h16[(size_t)n * 64 + lane]);   // self-row from shadow (L3-resident)
    float a0 = hs * d0;     // self-loop: src-side factor = dinv_k[n]
    float a1 = hs * d1;
    float a2 = hs * d2;
    int s0 = padded ? (n << 6) : rowst[n];
    int s1 = s0 + (padded ? min(cnt[n], PSTR) : (rowst[n + 1] - rowst[n]));
    for (int s = s0; s < s1; s += 8) {
        float4 p[8];
#pragma unroll
        for (int u = 0; u < 8; ++u) {
            int idx = s + u;
            p[u] = pack[(idx < s1) ? idx : s0];
        }
        float hv[8];
#pragma unroll
        for (int u = 0; u < 8; ++u)
            hv[u] = __half2float(h16[(size_t)__float_as_int(p[u].w) * 64 + lane]);
#pragma unroll
        for (int u = 0; u < 8; ++u)
            hv[u] = (s + u < s1) ? hv[u] : 0.f;   // mask ONCE (1 select vs 3 muls)
#pragma unroll
        for (int u = 0; u < 8; ++u) {
            a0 = fmaf(hv[u], p[u].x, a0);
            a1 = fmaf(hv[u], p[u].y, a1);
            a2 = fmaf(hv[u], p[u].z, a2);
        }
    }
    agg16[(size_t)n * 192 + lane]       = __float2half(a0 * d0);
    agg16[(size_t)n * 192 + 64 + lane]  = __float2half(a1 * d1);
    agg16[(size_t)n * 192 + 128 + lane] = __float2half(a2 * d2);
}

// ---------------- GEMM v3: fp16-pair LDS tiles + v_dot2_f32_f16 inner loop ----------------
// anp[kk][r] = half2(agg[r][2kk],agg[r][2kk+1]); wp[kk][c] = half2(W[2kk][c],W[2kk+1][c])
// per kk: 2x ds_read_b128 + 16 dot2 per thread. LDS 17.4KB -> 8 blocks/CU.
__global__ __launch_bounds__(256) void gemm_kernel(const __half* __restrict__ agg16,
                                                   const unsigned int* __restrict__ w16p,
                                                   const float* __restrict__ convb,
                                                   float* __restrict__ h,
                                                   __half* __restrict__ h16,
                                                   int layer, int dorelu) {
    __shared__ unsigned int anp[32 * 68];   // [kk][r] pad 68
    __shared__ unsigned int wp[32 * 68];    // [kk][c] pad 68
    int t = threadIdx.x;
    int n0 = blockIdx.x * 64;
    const unsigned int* Wp = w16p + (size_t)layer * 96 * 64;
    const float* B = convb + (size_t)layer * 192;
    int nb = t >> 4, cb = t & 15;
    float acc[4][4] = {{0.f}};

    unsigned int fa[8], fw[8];
    // prefetch kc=0: agg pairs (coalesced row-major), W pairs (preconverted)
#pragma unroll
    for (int rep = 0; rep < 8; ++rep) {
        int flat = rep * 256 + t;
        int r = flat >> 5, kk = flat & 31;
        int n = n0 + r;
        fa[rep] = (n < NN) ? *(const unsigned int*)&agg16[(size_t)n * 192 + kk * 2] : 0u;
        int kg = flat >> 6, c = flat & 63;
        fw[rep] = Wp[(size_t)kg * 64 + c];
    }

    for (int kc = 0; kc < 3; ++kc) {
        __syncthreads();                 // previous compute done reading LDS
#pragma unroll
        for (int rep = 0; rep < 8; ++rep) {
            int flat = rep * 256 + t;
            int r = flat >> 5, kk = flat & 31;
            anp[kk * 68 + r] = fa[rep];            // transposed store
            int kg = flat >> 6, c = flat & 63;
            wp[(kg & 31) * 68 + c] = fw[rep];
        }
        __syncthreads();
        if (kc < 2) {                    // issue next chunk's loads NOW
#pragma unroll
            for (int rep = 0; rep < 8; ++rep) {
                int flat = rep * 256 + t;
                int r = flat >> 5, kk = flat & 31;
                int n = n0 + r;
                fa[rep] = (n < NN) ? *(const unsigned int*)&agg16[(size_t)n * 192 + (kc + 1) * 64 + kk * 2] : 0u;
                int kg = flat >> 6, c = flat & 63;
                fw[rep] = Wp[((size_t)(kc + 1) * 32 + kg) * 64 + c];
            }
        }
#pragma unroll 8
        for (int kk = 0; kk < 32; ++kk) {
            uint4 av = *(const uint4*)&anp[kk * 68 + nb * 4];
            uint4 wv = *(const uint4*)&wp[kk * 68 + cb * 4];
            const unsigned int avr[4] = { av.x, av.y, av.z, av.w };
            const unsigned int wvc[4] = { wv.x, wv.y, wv.z, wv.w };
#pragma unroll
            for (int r = 0; r < 4; ++r) {
#pragma unroll
                for (int c = 0; c < 4; ++c)
                    acc[r][c] = dot2acc(avr[r], wvc[c], acc[r][c]);
            }
        }
    }

    int col0 = cb * 4;
    float bs[4];
#pragma unroll
    for (int c = 0; c < 4; ++c) {
        int col = col0 + c;
        bs[c] = B[col] + B[64 + col] + B[128 + col];
    }
#pragma unroll
    for (int r = 0; r < 4; ++r) {
        int n = n0 + nb * 4 + r;
        if (n < NN) {
            float4 hv = *(const float4*)&h[(size_t)n * 64 + col0];
            float v0 = acc[r][0] + bs[0];
            float v1 = acc[r][1] + bs[1];
            float v2 = acc[r][2] + bs[2];
            float v3 = acc[r][3] + bs[3];
            if (dorelu) {
                v0 = fmaxf(v0, 0.f); v1 = fmaxf(v1, 0.f);
                v2 = fmaxf(v2, 0.f); v3 = fmaxf(v3, 0.f);
            }
            float4 o;
            o.x = v0 + hv.x; o.y = v1 + hv.y; o.z = v2 + hv.z; o.w = v3 + hv.w;
            *(float4*)&h[(size_t)n * 64 + col0] = o;
            union { __half hh[4]; unsigned long long u; } pk;
            pk.hh[0] = __float2half(o.x);
            pk.hh[1] = __float2half(o.y);
            pk.hh[2] = __float2half(o.z);
            pk.hh[3] = __float2half(o.w);
            *(unsigned long long*)&h16[(size_t)n * 64 + col0] = pk.u;
        }
    }
}

// ---------------- graph start offsets via binary search (batch is sorted) ----------------
__global__ __launch_bounds__(256) void gstart_kernel(const int* __restrict__ batch,
                                                     int* __restrict__ gstart) {
    int g = blockIdx.x * 256 + threadIdx.x;
    if (g > GG) return;
    int lo = 0, hi = NN;
    while (lo < hi) {
        int mid = (lo + hi) >> 1;
        if (batch[mid] < g) lo = mid + 1; else hi = mid;
    }
    gstart[g] = lo;
}

// ---------------- mean pool: one block (4 waves) per graph ----------------
__global__ __launch_bounds__(256) void pool_kernel(const float* __restrict__ h,
                                                   const int* __restrict__ gstart,
                                                   float* __restrict__ hg) {
    __shared__ float red[3][64];
    int g = blockIdx.x;
    int w = threadIdx.x >> 6, lane = threadIdx.x & 63;
    int s = gstart[g], e = gstart[g + 1];
    float sum = 0.f;
    for (int n = s + w; n < e; n += 4) sum += h[(size_t)n * 64 + lane];
    if (w) red[w - 1][lane] = sum;
    __syncthreads();
    if (w == 0) {
        sum += red[0][lane] + red[1][lane] + red[2][lane];
        int c = e - s;
        hg[(size_t)g * 64 + lane] = sum / (float)(c > 0 ? c : 1);
    }
}

// ---------------- fc: 3 stacked linears, one wave per graph ----------------
__global__ __launch_bounds__(256) void fc_kernel(const float* __restrict__ hg,
                                                 const float* __restrict__ W1, const float* __restrict__ b1,
                                                 const float* __restrict__ W2, const float* __restrict__ b2,
                                                 const float* __restrict__ W3, const float* __restrict__ b3,
                                                 float* __restrict__ out) {
    int g = (blockIdx.x * 256 + threadIdx.x) >> 6;
    int lane = threadIdx.x & 63;
    if (g >= GG) return;
    float x = hg[(size_t)g * 64 + lane];
    float t1 = b1[lane];
    for (int i = 0; i < 64; ++i) t1 = fmaf(__shfl(x, i, 64), W1[i * 64 + lane], t1);
    float t2 = b2[lane];
    for (int i = 0; i < 64; ++i) t2 = fmaf(__shfl(t1, i, 64), W2[i * 64 + lane], t2);
    float p = t2 * W3[lane];
    for (int off = 32; off > 0; off >>= 1) p += __shfl_down(p, off, 64);
    if (lane == 0) out[g] = p + b3[0];
}

extern "C" void kernel_launch(void* const* d_in, const int* in_sizes, int n_in,
                              void* d_out, int out_size, void* d_ws, size_t ws_size,
                              hipStream_t stream) {
    const int*   x_atom = (const int*)d_in[0];
    const int*   ei     = (const int*)d_in[1];
    const float* ea     = (const float*)d_in[2];
    const int*   batch  = (const int*)d_in[3];
    const float* emb    = (const float*)d_in[4];
    const float* convW  = (const float*)d_in[5];
    const float* convb  = (const float*)d_in[6];
    const float* W1 = (const float*)d_in[7];  const float* b1 = (const float*)d_in[8];
    const float* W2 = (const float*)d_in[9];  const float* b2 = (const float*)d_in[10];
    const float* W3 = (const float*)d_in[11]; const float* b3 = (const float*)d_in[12];
    float* out = (float*)d_out;

    char* p = (char*)d_ws;
    size_t used = 0;
    auto alloc = [&](size_t bytes) -> void* {
        void* r = (void*)p;
        size_t rb = (bytes + 255) & ~(size_t)255;
        p += rb; used += rb;
        return r;
    };
    float*  h     = (float*)alloc((size_t)NN * 64 * 4);       // 25.6 MB
    __half* h16   = (__half*)alloc((size_t)NN * 64 * 2);      // 12.8 MB (gather shadow)
    __half* agg16 = (__half*)alloc((size_t)NN * 192 * 2);     // 38.4 MB (fp16 intermediate)
    unsigned int* w16p = (unsigned int*)alloc((size_t)LL * 96 * 64 * 4);  // 74KB fp16 W pairs
    float*  dinv  = (float*)alloc((size_t)3 * NN * 4);        // 1.2 MB
    int*    hist  = (int*)alloc((size_t)NN * 4);
    int*    rowst = (int*)alloc((size_t)(NN + 1) * 4);
    int*    fill  = (int*)alloc((size_t)NN * 4);
    int*    bsum  = (int*)alloc(128 * 4);
    int*    boff  = (int*)alloc(128 * 4);
    int*    gstart= (int*)alloc((size_t)(GG + 1) * 4);
    float*  hg    = (float*)alloc((size_t)GG * 64 * 4);
    // pack last: padded (102.4 MB) if workspace allows, else compact (19.2 MB, +8 slot margin)
    size_t padded_pack  = (size_t)NN * PSTR * 16;
    size_t compact_pack = (size_t)(EE + 8) * 16;
    int padded = (ws_size >= used + padded_pack) ? 1 : 0;
    float4* pack = (float4*)alloc(padded ? padded_pack : compact_pack);

    // ---- encoder + W conversion + CSR build ----
    enc_kernel<<<(NN * 64) / 256, 256, 0, stream>>>(x_atom, emb, h, h16);
    wcvt_kernel<<<(LL * 96 * 64 + 255) / 256, 256, 0, stream>>>(convW, w16p);
    init_kernel<<<(NN + 255) / 256, 256, 0, stream>>>(hist, fill);
    if (!padded) {
        hist_kernel<<<(EE + 255) / 256, 256, 0, stream>>>(ei, hist);
        scan1_kernel<<<SCAN_NB, 256, 0, stream>>>(hist, bsum);
        scan2_kernel<<<1, 64, 0, stream>>>(bsum, boff, rowst);
        scan3_kernel<<<SCAN_NB, 256, 0, stream>>>(hist, boff, rowst);
    }
    fill_kernel<<<FILL_NB, 256, 0, stream>>>(ei, ea, rowst, fill, pack, padded);
    degdinv_kernel<<<(NN * 16 + 255) / 256, 256, 0, stream>>>(pack, rowst, fill, dinv, padded);
    normpack_kernel<<<(NN * 16 + 255) / 256, 256, 0, stream>>>(dinv, rowst, fill, pack, padded);
    gstart_kernel<<<(GG + 1 + 255) / 256, 256, 0, stream>>>(batch, gstart);

    // ---- 3 GCN layers: aggregate-then-GEMM (linearity refactor) ----
    for (int layer = 0; layer < LL; ++layer) {
        agg_kernel<<<NN / 4, 256, 0, stream>>>(h16, pack, rowst, fill, dinv, agg16, padded);
        gemm_kernel<<<(NN + 63) / 64, 256, 0, stream>>>(agg16, w16p, convb, h, h16, layer,
                                                        (layer < LL - 1) ? 1 : 0);
    }

    // ---- pool + fc ----
    pool_kernel<<<GG, 256, 0, stream>>>(h, gstart, hg);
    fc_kernel<<<GG / 4, 256, 0, stream>>>(hg, W1, b1, W2, b2, W3, b3, out);
}

// Round 18
// 358.462 us; speedup vs baseline: 1.5432x; 1.2333x over previous
//
#include <hip/hip_runtime.h>
#include <hip/hip_fp16.h>
#include <math.h>

#define NN 100000
#define EE 1200000
#define DD 64
#define GG 1024
#define LL 3
#define VOCAB 128
#define SCAN_NB 98     // ceil(100000/1024)
#define PSTR 64        // padded CSR row stride (slots/node); Poisson(12) max-deg << 64
#define FILL_NB 2048   // fill grid: 8 blocks/CU

// fp16 pair dot with fp32 accumulate; fallback keeps compile safe everywhere
__device__ __forceinline__ float dot2acc(unsigned int a, unsigned int b, float c) {
#if defined(__has_builtin)
#if __has_builtin(__builtin_amdgcn_fdot2)
    typedef _Float16 h2v __attribute__((ext_vector_type(2)));
    union U { unsigned int u; h2v v; };
    U ua, ub; ua.u = a; ub.u = b;
    return __builtin_amdgcn_fdot2(ua.v, ub.v, c, false);
#else
    __half2 ha = *(__half2*)&a, hb = *(__half2*)&b;
    float2 f1 = __half22float2(ha), f2 = __half22float2(hb);
    return fmaf(f1.x, f2.x, fmaf(f1.y, f2.y, c));
#endif
#else
    __half2 ha = *(__half2*)&a, hb = *(__half2*)&b;
    float2 f1 = __half22float2(ha), f2 = __half22float2(hb);
    return fmaf(f1.x, f2.x, fmaf(f1.y, f2.y, c));
#endif
}

// ---------------- encoder: h[n][j] = sum_f emb[f][x_atom[n][f]][j] (+ fp16 shadow) ----------------
__global__ __launch_bounds__(256) void enc_kernel(const int* __restrict__ x_atom,
                                                  const float* __restrict__ emb,
                                                  float* __restrict__ h,
                                                  __half* __restrict__ h16) {
    int idx = blockIdx.x * 256 + threadIdx.x;      // n*64 + j
    if (idx >= NN * 64) return;
    int n = idx >> 6, j = idx & 63;
    int v0 = x_atom[n * 3 + 0];
    int v1 = x_atom[n * 3 + 1];
    int v2 = x_atom[n * 3 + 2];
    float v = emb[(0 * VOCAB + v0) * 64 + j]
            + emb[(1 * VOCAB + v1) * 64 + j]
            + emb[(2 * VOCAB + v2) * 64 + j];
    h[idx] = v;
    h16[idx] = __float2half(v);
}

// ---------------- one-time: pack convW into fp16 k-pairs w16p[layer][96][64] ----------------
__global__ __launch_bounds__(256) void wcvt_kernel(const float* __restrict__ convW,
                                                   unsigned int* __restrict__ w16p) {
    int idx = blockIdx.x * 256 + threadIdx.x;      // layer*96*64 + p*64 + c
    if (idx >= LL * 96 * 64) return;
    int l = idx / (96 * 64);
    int rem = idx - l * 96 * 64;
    int pr = rem >> 6, c = rem & 63;
    const float* W = convW + (size_t)l * 192 * 64;
    __half2 hh = __floats2half2_rn(W[(2 * pr) * 64 + c], W[(2 * pr + 1) * 64 + c]);
    w16p[idx] = *(unsigned int*)&hh;
}

// ---------------- init: hist=0, fill=0 ----------------
__global__ __launch_bounds__(256) void init_kernel(int* __restrict__ hist,
                                                   int* __restrict__ fill) {
    int i = blockIdx.x * 256 + threadIdx.x;
    if (i < NN) { hist[i] = 0; fill[i] = 0; }
}

// ---------------- in-degree histogram (compact fallback path only) ----------------
__global__ __launch_bounds__(256) void hist_kernel(const int* __restrict__ ei,
                                                   int* __restrict__ hist) {
    int e = blockIdx.x * 256 + threadIdx.x;
    if (e >= EE) return;
    atomicAdd(&hist[ei[EE + e]], 1);
}

// ---------------- scan stage 1 (fallback) ----------------
__global__ __launch_bounds__(256) void scan1_kernel(const int* __restrict__ hist,
                                                    int* __restrict__ bsum) {
    __shared__ int sd[256];
    int t = threadIdx.x, b = blockIdx.x;
    int base = b * 1024 + t * 4;
    int s = 0;
#pragma unroll
    for (int u = 0; u < 4; ++u) { int i = base + u; if (i < NN) s += hist[i]; }
    sd[t] = s;
    __syncthreads();
    for (int off = 128; off > 0; off >>= 1) {
        if (t < off) sd[t] += sd[t + off];
        __syncthreads();
    }
    if (t == 0) bsum[b] = sd[0];
}

// ---------------- scan stage 2 (fallback) ----------------
__global__ void scan2_kernel(const int* __restrict__ bsum, int* __restrict__ boff,
                             int* __restrict__ rowst) {
    if (threadIdx.x == 0 && blockIdx.x == 0) {
        int acc = 0;
        for (int i = 0; i < SCAN_NB; ++i) { boff[i] = acc; acc += bsum[i]; }
        rowst[NN] = acc;   // == EE
    }
}

// ---------------- scan stage 3 (fallback) ----------------
__global__ __launch_bounds__(256) void scan3_kernel(const int* __restrict__ hist,
                                                    const int* __restrict__ boff,
                                                    int* __restrict__ rowst) {
    __shared__ int sd[256];
    int t = threadIdx.x, b = blockIdx.x;
    int base = b * 1024 + t * 4;
    int v[4]; int s = 0;
#pragma unroll
    for (int u = 0; u < 4; ++u) {
        int i = base + u;
        v[u] = (i < NN) ? hist[i] : 0;
        s += v[u];
    }
    sd[t] = s;
    __syncthreads();
    for (int off = 1; off < 256; off <<= 1) {
        int a = (t >= off) ? sd[t - off] : 0;
        __syncthreads();
        sd[t] += a;
        __syncthreads();
    }
    int texcl = sd[t] - s;
    int o = boff[b] + texcl;
#pragma unroll
    for (int u = 0; u < 4; ++u) {
        int i = base + u;
        if (i < NN) rowst[i] = o;
        o += v[u];
    }
}

// ---------------- CSR fill: direct 16B pack scatter (known wall ~80us) ----------------
__global__ __launch_bounds__(256) void fill_kernel(const int* __restrict__ ei,
                                                   const float* __restrict__ ea,
                                                   const int* __restrict__ rowst,
                                                   int* __restrict__ fill,
                                                   float4* __restrict__ pack,
                                                   int padded) {
    const int T = FILL_NB * 256;                 // 524288 threads total
    int t0 = blockIdx.x * 256 + threadIdx.x;
    int e[3] = { t0, t0 + T, t0 + 2 * T };
    int d[3]; float4 p[3]; bool v[3];
#pragma unroll
    for (int u = 0; u < 3; ++u) {
        v[u] = (e[u] < EE);
        if (v[u]) {
            int s = ei[e[u]];
            d[u] = ei[EE + e[u]];
            p[u].x = ea[e[u] * 3 + 0];
            p[u].y = ea[e[u] * 3 + 1];
            p[u].z = ea[e[u] * 3 + 2];
            p[u].w = __int_as_float(s);
        }
    }
    int pos[3];
#pragma unroll
    for (int u = 0; u < 3; ++u)
        if (v[u]) pos[u] = atomicAdd(&fill[d[u]], 1);
#pragma unroll
    for (int u = 0; u < 3; ++u) {
        if (v[u]) {
            if (padded) {
                if (pos[u] < PSTR) pack[((size_t)d[u] << 6) + pos[u]] = p[u];
            } else {
                pack[rowst[d[u]] + pos[u]] = p[u];
            }
        }
    }
}

// ---------------- weighted degree: 16-lane group per node, parallel row-sum ----------------
__global__ __launch_bounds__(256) void degdinv_kernel(const float4* __restrict__ pack,
                                                      const int* __restrict__ rowst,
                                                      const int* __restrict__ cnt,
                                                      float* __restrict__ dinv,
                                                      int padded) {
    int n   = (blockIdx.x * 256 + threadIdx.x) >> 4;
    int sub = threadIdx.x & 15;
    if (n >= NN) return;
    int s0 = padded ? (n << 6) : rowst[n];
    int c  = padded ? min(cnt[n], PSTR) : (rowst[n + 1] - rowst[n]);
    float d0 = 0.f, d1 = 0.f, d2 = 0.f;
    for (int s = sub; s < c; s += 16) {
        float4 p = pack[s0 + s];
        d0 += p.x; d1 += p.y; d2 += p.z;
    }
#pragma unroll
    for (int off = 8; off > 0; off >>= 1) {
        d0 += __shfl_down(d0, off, 16);
        d1 += __shfl_down(d1, off, 16);
        d2 += __shfl_down(d2, off, 16);
    }
    if (sub == 0) {
        d0 += 1.0f; d1 += 1.0f; d2 += 1.0f;   // self-loop weight 1
        dinv[n]          = 1.0f / sqrtf(d0);
        dinv[NN + n]     = 1.0f / sqrtf(d1);
        dinv[2 * NN + n] = 1.0f / sqrtf(d2);
    }
}

// ---------------- fold SOURCE-side dinv into pack (dst side applied in agg) ----------------
__global__ __launch_bounds__(256) void normpack_kernel(const float* __restrict__ dinv,
                                                       const int* __restrict__ rowst,
                                                       const int* __restrict__ cnt,
                                                       float4* __restrict__ pack,
                                                       int padded) {
    int n   = (blockIdx.x * 256 + threadIdx.x) >> 4;
    int sub = threadIdx.x & 15;
    if (n >= NN) return;
    int s0 = padded ? (n << 6) : rowst[n];
    int c  = padded ? min(cnt[n], PSTR) : (rowst[n + 1] - rowst[n]);
    for (int s = sub; s < c; s += 16) {
        float4 p = pack[s0 + s];
        int src = __float_as_int(p.w);
        p.x *= dinv[src];
        p.y *= dinv[NN + src];
        p.z *= dinv[2 * NN + src];
        pack[s0 + s] = p;
    }
}

// ---------------- aggregation v2: TWO nodes per wave (32 lanes each, feature-pairs) ----------
// Doubles in-flight gather rows per CU at unchanged occupancy/VGPR. Lanes 0-31 = node A,
// 32-63 = node B; each lane owns features (2*sub, 2*sub+1) via one half2 load.
__global__ __launch_bounds__(256) void agg_kernel(const __half* __restrict__ h16,
                                                  const float4* __restrict__ pack,
                                                  const int* __restrict__ rowst,
                                                  const int* __restrict__ cnt,
                                                  const float* __restrict__ dinv,
                                                  __half* __restrict__ agg16,
                                                  int padded) {
    int wid  = (blockIdx.x * 256 + threadIdx.x) >> 6;
    int lane = threadIdx.x & 63;
    int half = lane >> 5;
    int sub  = lane & 31;
    int n = wid * 2 + half;
    if (n >= NN) return;
    float d0 = dinv[n], d1 = dinv[NN + n], d2 = dinv[2 * NN + n];
    unsigned int hsu = *(const unsigned int*)&h16[((unsigned int)n << 6) + 2 * sub];
    float2 hs = __half22float2(*(__half2*)&hsu);
    float2 a0 = make_float2(hs.x * d0, hs.y * d0);   // self-loop (src-side factor)
    float2 a1 = make_float2(hs.x * d1, hs.y * d1);
    float2 a2 = make_float2(hs.x * d2, hs.y * d2);
    int s0 = padded ? (n << 6) : rowst[n];
    int s1 = s0 + (padded ? min(cnt[n], PSTR) : (rowst[n + 1] - rowst[n]));
    for (int s = s0; s < s1; s += 8) {
        float4 p[8];
#pragma unroll
        for (int u = 0; u < 8; ++u) {
            int idx = s + u;
            p[u] = pack[(idx < s1) ? idx : s0];
        }
        unsigned int hv[8];
#pragma unroll
        for (int u = 0; u < 8; ++u)
            hv[u] = *(const unsigned int*)&h16[((unsigned int)__float_as_int(p[u].w) << 6) + 2 * sub];
#pragma unroll
        for (int u = 0; u < 8; ++u) {
            float2 hf = __half22float2(*(__half2*)&hv[u]);
            float m = (s + u < s1) ? 1.f : 0.f;
            hf.x *= m; hf.y *= m;
            a0.x = fmaf(hf.x, p[u].x, a0.x); a0.y = fmaf(hf.y, p[u].x, a0.y);
            a1.x = fmaf(hf.x, p[u].y, a1.x); a1.y = fmaf(hf.y, p[u].y, a1.y);
            a2.x = fmaf(hf.x, p[u].z, a2.x); a2.y = fmaf(hf.y, p[u].z, a2.y);
        }
    }
    unsigned int base = (unsigned int)n * 192 + 2 * sub;
    __half2 o0 = __floats2half2_rn(a0.x * d0, a0.y * d0);
    __half2 o1 = __floats2half2_rn(a1.x * d1, a1.y * d1);
    __half2 o2 = __floats2half2_rn(a2.x * d2, a2.y * d2);
    *(unsigned int*)&agg16[base]       = *(unsigned int*)&o0;
    *(unsigned int*)&agg16[base + 64]  = *(unsigned int*)&o1;
    *(unsigned int*)&agg16[base + 128] = *(unsigned int*)&o2;
}

// ---------------- GEMM v3: fp16-pair LDS tiles + v_dot2_f32_f16 inner loop ----------------
__global__ __launch_bounds__(256) void gemm_kernel(const __half* __restrict__ agg16,
                                                   const unsigned int* __restrict__ w16p,
                                                   const float* __restrict__ convb,
                                                   float* __restrict__ h,
                                                   __half* __restrict__ h16,
                                                   int layer, int dorelu) {
    __shared__ unsigned int anp[32 * 68];   // [kk][r] pad 68
    __shared__ unsigned int wp[32 * 68];    // [kk][c] pad 68
    int t = threadIdx.x;
    int n0 = blockIdx.x * 64;
    const unsigned int* Wp = w16p + (size_t)layer * 96 * 64;
    const float* B = convb + (size_t)layer * 192;
    int nb = t >> 4, cb = t & 15;
    float acc[4][4] = {{0.f}};

    unsigned int fa[8], fw[8];
#pragma unroll
    for (int rep = 0; rep < 8; ++rep) {
        int flat = rep * 256 + t;
        int r = flat >> 5, kk = flat & 31;
        int n = n0 + r;
        fa[rep] = (n < NN) ? *(const unsigned int*)&agg16[(size_t)n * 192 + kk * 2] : 0u;
        int kg = flat >> 6, c = flat & 63;
        fw[rep] = Wp[(size_t)kg * 64 + c];
    }

    for (int kc = 0; kc < 3; ++kc) {
        __syncthreads();
#pragma unroll
        for (int rep = 0; rep < 8; ++rep) {
            int flat = rep * 256 + t;
            int r = flat >> 5, kk = flat & 31;
            anp[kk * 68 + r] = fa[rep];            // transposed store
            int kg = flat >> 6, c = flat & 63;
            wp[(kg & 31) * 68 + c] = fw[rep];
        }
        __syncthreads();
        if (kc < 2) {
#pragma unroll
            for (int rep = 0; rep < 8; ++rep) {
                int flat = rep * 256 + t;
                int r = flat >> 5, kk = flat & 31;
                int n = n0 + r;
                fa[rep] = (n < NN) ? *(const unsigned int*)&agg16[(size_t)n * 192 + (kc + 1) * 64 + kk * 2] : 0u;
                int kg = flat >> 6, c = flat & 63;
                fw[rep] = Wp[((size_t)(kc + 1) * 32 + kg) * 64 + c];
            }
        }
#pragma unroll 8
        for (int kk = 0; kk < 32; ++kk) {
            uint4 av = *(const uint4*)&anp[kk * 68 + nb * 4];
            uint4 wv = *(const uint4*)&wp[kk * 68 + cb * 4];
            const unsigned int avr[4] = { av.x, av.y, av.z, av.w };
            const unsigned int wvc[4] = { wv.x, wv.y, wv.z, wv.w };
#pragma unroll
            for (int r = 0; r < 4; ++r) {
#pragma unroll
                for (int c = 0; c < 4; ++c)
                    acc[r][c] = dot2acc(avr[r], wvc[c], acc[r][c]);
            }
        }
    }

    int col0 = cb * 4;
    float bs[4];
#pragma unroll
    for (int c = 0; c < 4; ++c) {
        int col = col0 + c;
        bs[c] = B[col] + B[64 + col] + B[128 + col];
    }
#pragma unroll
    for (int r = 0; r < 4; ++r) {
        int n = n0 + nb * 4 + r;
        if (n < NN) {
            float4 hv = *(const float4*)&h[(size_t)n * 64 + col0];
            float v0 = acc[r][0] + bs[0];
            float v1 = acc[r][1] + bs[1];
            float v2 = acc[r][2] + bs[2];
            float v3 = acc[r][3] + bs[3];
            if (dorelu) {
                v0 = fmaxf(v0, 0.f); v1 = fmaxf(v1, 0.f);
                v2 = fmaxf(v2, 0.f); v3 = fmaxf(v3, 0.f);
            }
            float4 o;
            o.x = v0 + hv.x; o.y = v1 + hv.y; o.z = v2 + hv.z; o.w = v3 + hv.w;
            *(float4*)&h[(size_t)n * 64 + col0] = o;
            union { __half hh[4]; unsigned long long u; } pk;
            pk.hh[0] = __float2half(o.x);
            pk.hh[1] = __float2half(o.y);
            pk.hh[2] = __float2half(o.z);
            pk.hh[3] = __float2half(o.w);
            *(unsigned long long*)&h16[(size_t)n * 64 + col0] = pk.u;
        }
    }
}

// ---------------- graph start offsets via binary search (batch is sorted) ----------------
__global__ __launch_bounds__(256) void gstart_kernel(const int* __restrict__ batch,
                                                     int* __restrict__ gstart) {
    int g = blockIdx.x * 256 + threadIdx.x;
    if (g > GG) return;
    int lo = 0, hi = NN;
    while (lo < hi) {
        int mid = (lo + hi) >> 1;
        if (batch[mid] < g) lo = mid + 1; else hi = mid;
    }
    gstart[g] = lo;
}

// ---------------- mean pool: one block (4 waves) per graph ----------------
__global__ __launch_bounds__(256) void pool_kernel(const float* __restrict__ h,
                                                   const int* __restrict__ gstart,
                                                   float* __restrict__ hg) {
    __shared__ float red[3][64];
    int g = blockIdx.x;
    int w = threadIdx.x >> 6, lane = threadIdx.x & 63;
    int s = gstart[g], e = gstart[g + 1];
    float sum = 0.f;
    for (int n = s + w; n < e; n += 4) sum += h[(size_t)n * 64 + lane];
    if (w) red[w - 1][lane] = sum;
    __syncthreads();
    if (w == 0) {
        sum += red[0][lane] + red[1][lane] + red[2][lane];
        int c = e - s;
        hg[(size_t)g * 64 + lane] = sum / (float)(c > 0 ? c : 1);
    }
}

// ---------------- fc: 3 stacked linears, one wave per graph ----------------
__global__ __launch_bounds__(256) void fc_kernel(const float* __restrict__ hg,
                                                 const float* __restrict__ W1, const float* __restrict__ b1,
                                                 const float* __restrict__ W2, const float* __restrict__ b2,
                                                 const float* __restrict__ W3, const float* __restrict__ b3,
                                                 float* __restrict__ out) {
    int g = (blockIdx.x * 256 + threadIdx.x) >> 6;
    int lane = threadIdx.x & 63;
    if (g >= GG) return;
    float x = hg[(size_t)g * 64 + lane];
    float t1 = b1[lane];
    for (int i = 0; i < 64; ++i) t1 = fmaf(__shfl(x, i, 64), W1[i * 64 + lane], t1);
    float t2 = b2[lane];
    for (int i = 0; i < 64; ++i) t2 = fmaf(__shfl(t1, i, 64), W2[i * 64 + lane], t2);
    float p = t2 * W3[lane];
    for (int off = 32; off > 0; off >>= 1) p += __shfl_down(p, off, 64);
    if (lane == 0) out[g] = p + b3[0];
}

extern "C" void kernel_launch(void* const* d_in, const int* in_sizes, int n_in,
                              void* d_out, int out_size, void* d_ws, size_t ws_size,
                              hipStream_t stream) {
    const int*   x_atom = (const int*)d_in[0];
    const int*   ei     = (const int*)d_in[1];
    const float* ea     = (const float*)d_in[2];
    const int*   batch  = (const int*)d_in[3];
    const float* emb    = (const float*)d_in[4];
    const float* convW  = (const float*)d_in[5];
    const float* convb  = (const float*)d_in[6];
    const float* W1 = (const float*)d_in[7];  const float* b1 = (const float*)d_in[8];
    const float* W2 = (const float*)d_in[9];  const float* b2 = (const float*)d_in[10];
    const float* W3 = (const float*)d_in[11]; const float* b3 = (const float*)d_in[12];
    float* out = (float*)d_out;

    char* p = (char*)d_ws;
    size_t used = 0;
    auto alloc = [&](size_t bytes) -> void* {
        void* r = (void*)p;
        size_t rb = (bytes + 255) & ~(size_t)255;
        p += rb; used += rb;
        return r;
    };
    float*  h     = (float*)alloc((size_t)NN * 64 * 4);       // 25.6 MB
    __half* h16   = (__half*)alloc((size_t)NN * 64 * 2);      // 12.8 MB (gather shadow)
    __half* agg16 = (__half*)alloc((size_t)NN * 192 * 2);     // 38.4 MB (fp16 intermediate)
    unsigned int* w16p = (unsigned int*)alloc((size_t)LL * 96 * 64 * 4);  // 74KB fp16 W pairs
    float*  dinv  = (float*)alloc((size_t)3 * NN * 4);        // 1.2 MB
    int*    hist  = (int*)alloc((size_t)NN * 4);
    int*    rowst = (int*)alloc((size_t)(NN + 1) * 4);
    int*    fill  = (int*)alloc((size_t)NN * 4);
    int*    bsum  = (int*)alloc(128 * 4);
    int*    boff  = (int*)alloc(128 * 4);
    int*    gstart= (int*)alloc((size_t)(GG + 1) * 4);
    float*  hg    = (float*)alloc((size_t)GG * 64 * 4);
    // pack last: padded (102.4 MB) if workspace allows, else compact (19.2 MB, +8 slot margin)
    size_t padded_pack  = (size_t)NN * PSTR * 16;
    size_t compact_pack = (size_t)(EE + 8) * 16;
    int padded = (ws_size >= used + padded_pack) ? 1 : 0;
    float4* pack = (float4*)alloc(padded ? padded_pack : compact_pack);

    // ---- encoder + W conversion + CSR build ----
    enc_kernel<<<(NN * 64) / 256, 256, 0, stream>>>(x_atom, emb, h, h16);
    wcvt_kernel<<<(LL * 96 * 64 + 255) / 256, 256, 0, stream>>>(convW, w16p);
    init_kernel<<<(NN + 255) / 256, 256, 0, stream>>>(hist, fill);
    if (!padded) {
        hist_kernel<<<(EE + 255) / 256, 256, 0, stream>>>(ei, hist);
        scan1_kernel<<<SCAN_NB, 256, 0, stream>>>(hist, bsum);
        scan2_kernel<<<1, 64, 0, stream>>>(bsum, boff, rowst);
        scan3_kernel<<<SCAN_NB, 256, 0, stream>>>(hist, boff, rowst);
    }
    fill_kernel<<<FILL_NB, 256, 0, stream>>>(ei, ea, rowst, fill, pack, padded);
    degdinv_kernel<<<(NN * 16 + 255) / 256, 256, 0, stream>>>(pack, rowst, fill, dinv, padded);
    normpack_kernel<<<(NN * 16 + 255) / 256, 256, 0, stream>>>(dinv, rowst, fill, pack, padded);
    gstart_kernel<<<(GG + 1 + 255) / 256, 256, 0, stream>>>(batch, gstart);

    // ---- 3 GCN layers: aggregate-then-GEMM (linearity refactor) ----
    const int aggblocks = (NN / 2 + 3) / 4;   // 2 nodes/wave, 4 waves/block
    for (int layer = 0; layer < LL; ++layer) {
        agg_kernel<<<aggblocks, 256, 0, stream>>>(h16, pack, rowst, fill, dinv, agg16, padded);
        gemm_kernel<<<(NN + 63) / 64, 256, 0, stream>>>(agg16, w16p, convb, h, h16, layer,
                                                        (layer < LL - 1) ? 1 : 0);
    }

    // ---- pool + fc ----
    pool_kernel<<<GG, 256, 0, stream>>>(h, gstart, hg);
    fc_kernel<<<GG / 4, 256, 0, stream>>>(hg, W1, b1, W2, b2, W3, b3, out);
}

// Round 19
// 354.067 us; speedup vs baseline: 1.5624x; 1.0124x over previous
//
#include <hip/hip_runtime.h>
#include <hip/hip_fp16.h>
#include <math.h>

#define NN 100000
#define EE 1200000
#define DD 64
#define GG 1024
#define LL 3
#define VOCAB 128
#define SCAN_NB 98     // ceil(100000/1024)
#define PSTR 64        // padded CSR row stride (slots/node); Poisson(12) max-deg << 64
#define FILL_NB 2048   // fill grid: 8 blocks/CU

// fp16 pair dot with fp32 accumulate; fallback keeps compile safe everywhere
__device__ __forceinline__ float dot2acc(unsigned int a, unsigned int b, float c) {
#if defined(__has_builtin)
#if __has_builtin(__builtin_amdgcn_fdot2)
    typedef _Float16 h2v __attribute__((ext_vector_type(2)));
    union U { unsigned int u; h2v v; };
    U ua, ub; ua.u = a; ub.u = b;
    return __builtin_amdgcn_fdot2(ua.v, ub.v, c, false);
#else
    __half2 ha = *(__half2*)&a, hb = *(__half2*)&b;
    float2 f1 = __half22float2(ha), f2 = __half22float2(hb);
    return fmaf(f1.x, f2.x, fmaf(f1.y, f2.y, c));
#endif
#else
    __half2 ha = *(__half2*)&a, hb = *(__half2*)&b;
    float2 f1 = __half22float2(ha), f2 = __half22float2(hb);
    return fmaf(f1.x, f2.x, fmaf(f1.y, f2.y, c));
#endif
}

// ---------------- encoder: h[n][j] = sum_f emb[f][x_atom[n][f]][j] (+ fp16 shadow) ----------------
__global__ __launch_bounds__(256) void enc_kernel(const int* __restrict__ x_atom,
                                                  const float* __restrict__ emb,
                                                  float* __restrict__ h,
                                                  __half* __restrict__ h16) {
    int idx = blockIdx.x * 256 + threadIdx.x;      // n*64 + j
    if (idx >= NN * 64) return;
    int n = idx >> 6, j = idx & 63;
    int v0 = x_atom[n * 3 + 0];
    int v1 = x_atom[n * 3 + 1];
    int v2 = x_atom[n * 3 + 2];
    float v = emb[(0 * VOCAB + v0) * 64 + j]
            + emb[(1 * VOCAB + v1) * 64 + j]
            + emb[(2 * VOCAB + v2) * 64 + j];
    h[idx] = v;
    h16[idx] = __float2half(v);
}

// ---------------- one-time: pack convW into fp16 k-pairs w16p[layer][96][64] ----------------
__global__ __launch_bounds__(256) void wcvt_kernel(const float* __restrict__ convW,
                                                   unsigned int* __restrict__ w16p) {
    int idx = blockIdx.x * 256 + threadIdx.x;      // layer*96*64 + p*64 + c
    if (idx >= LL * 96 * 64) return;
    int l = idx / (96 * 64);
    int rem = idx - l * 96 * 64;
    int pr = rem >> 6, c = rem & 63;
    const float* W = convW + (size_t)l * 192 * 64;
    __half2 hh = __floats2half2_rn(W[(2 * pr) * 64 + c], W[(2 * pr + 1) * 64 + c]);
    w16p[idx] = *(unsigned int*)&hh;
}

// ---------------- init: hist=0, fill=0 ----------------
__global__ __launch_bounds__(256) void init_kernel(int* __restrict__ hist,
                                                   int* __restrict__ fill) {
    int i = blockIdx.x * 256 + threadIdx.x;
    if (i < NN) { hist[i] = 0; fill[i] = 0; }
}

// ---------------- in-degree histogram (compact fallback path only) ----------------
__global__ __launch_bounds__(256) void hist_kernel(const int* __restrict__ ei,
                                                   int* __restrict__ hist) {
    int e = blockIdx.x * 256 + threadIdx.x;
    if (e >= EE) return;
    atomicAdd(&hist[ei[EE + e]], 1);
}

// ---------------- scan stage 1 (fallback) ----------------
__global__ __launch_bounds__(256) void scan1_kernel(const int* __restrict__ hist,
                                                    int* __restrict__ bsum) {
    __shared__ int sd[256];
    int t = threadIdx.x, b = blockIdx.x;
    int base = b * 1024 + t * 4;
    int s = 0;
#pragma unroll
    for (int u = 0; u < 4; ++u) { int i = base + u; if (i < NN) s += hist[i]; }
    sd[t] = s;
    __syncthreads();
    for (int off = 128; off > 0; off >>= 1) {
        if (t < off) sd[t] += sd[t + off];
        __syncthreads();
    }
    if (t == 0) bsum[b] = sd[0];
}

// ---------------- scan stage 2 (fallback) ----------------
__global__ void scan2_kernel(const int* __restrict__ bsum, int* __restrict__ boff,
                             int* __restrict__ rowst) {
    if (threadIdx.x == 0 && blockIdx.x == 0) {
        int acc = 0;
        for (int i = 0; i < SCAN_NB; ++i) { boff[i] = acc; acc += bsum[i]; }
        rowst[NN] = acc;   // == EE
    }
}

// ---------------- scan stage 3 (fallback) ----------------
__global__ __launch_bounds__(256) void scan3_kernel(const int* __restrict__ hist,
                                                    const int* __restrict__ boff,
                                                    int* __restrict__ rowst) {
    __shared__ int sd[256];
    int t = threadIdx.x, b = blockIdx.x;
    int base = b * 1024 + t * 4;
    int v[4]; int s = 0;
#pragma unroll
    for (int u = 0; u < 4; ++u) {
        int i = base + u;
        v[u] = (i < NN) ? hist[i] : 0;
        s += v[u];
    }
    sd[t] = s;
    __syncthreads();
    for (int off = 1; off < 256; off <<= 1) {
        int a = (t >= off) ? sd[t - off] : 0;
        __syncthreads();
        sd[t] += a;
        __syncthreads();
    }
    int texcl = sd[t] - s;
    int o = boff[b] + texcl;
#pragma unroll
    for (int u = 0; u < 4; ++u) {
        int i = base + u;
        if (i < NN) rowst[i] = o;
        o += v[u];
    }
}

// ---------------- CSR fill: direct 16B pack scatter (known wall ~80us) ----------------
__global__ __launch_bounds__(256) void fill_kernel(const int* __restrict__ ei,
                                                   const float* __restrict__ ea,
                                                   const int* __restrict__ rowst,
                                                   int* __restrict__ fill,
                                                   float4* __restrict__ pack,
                                                   int padded) {
    const int T = FILL_NB * 256;                 // 524288 threads total
    int t0 = blockIdx.x * 256 + threadIdx.x;
    int e[3] = { t0, t0 + T, t0 + 2 * T };
    int d[3]; float4 p[3]; bool v[3];
#pragma unroll
    for (int u = 0; u < 3; ++u) {
        v[u] = (e[u] < EE);
        if (v[u]) {
            int s = ei[e[u]];
            d[u] = ei[EE + e[u]];
            p[u].x = ea[e[u] * 3 + 0];
            p[u].y = ea[e[u] * 3 + 1];
            p[u].z = ea[e[u] * 3 + 2];
            p[u].w = __int_as_float(s);
        }
    }
    int pos[3];
#pragma unroll
    for (int u = 0; u < 3; ++u)
        if (v[u]) pos[u] = atomicAdd(&fill[d[u]], 1);
#pragma unroll
    for (int u = 0; u < 3; ++u) {
        if (v[u]) {
            if (padded) {
                if (pos[u] < PSTR) pack[((size_t)d[u] << 6) + pos[u]] = p[u];
            } else {
                pack[rowst[d[u]] + pos[u]] = p[u];
            }
        }
    }
}

// ---------------- weighted degree: 16-lane group per node, parallel row-sum ----------------
__global__ __launch_bounds__(256) void degdinv_kernel(const float4* __restrict__ pack,
                                                      const int* __restrict__ rowst,
                                                      const int* __restrict__ cnt,
                                                      float* __restrict__ dinv,
                                                      int padded) {
    int n   = (blockIdx.x * 256 + threadIdx.x) >> 4;
    int sub = threadIdx.x & 15;
    if (n >= NN) return;
    int s0 = padded ? (n << 6) : rowst[n];
    int c  = padded ? min(cnt[n], PSTR) : (rowst[n + 1] - rowst[n]);
    float d0 = 0.f, d1 = 0.f, d2 = 0.f;
    for (int s = sub; s < c; s += 16) {
        float4 p = pack[s0 + s];
        d0 += p.x; d1 += p.y; d2 += p.z;
    }
#pragma unroll
    for (int off = 8; off > 0; off >>= 1) {
        d0 += __shfl_down(d0, off, 16);
        d1 += __shfl_down(d1, off, 16);
        d2 += __shfl_down(d2, off, 16);
    }
    if (sub == 0) {
        d0 += 1.0f; d1 += 1.0f; d2 += 1.0f;   // self-loop weight 1
        dinv[n]          = 1.0f / sqrtf(d0);
        dinv[NN + n]     = 1.0f / sqrtf(d1);
        dinv[2 * NN + n] = 1.0f / sqrtf(d2);
    }
}

// ---------------- fold SOURCE-side dinv into pack (dst side applied in agg) ----------------
__global__ __launch_bounds__(256) void normpack_kernel(const float* __restrict__ dinv,
                                                       const int* __restrict__ rowst,
                                                       const int* __restrict__ cnt,
                                                       float4* __restrict__ pack,
                                                       int padded) {
    int n   = (blockIdx.x * 256 + threadIdx.x) >> 4;
    int sub = threadIdx.x & 15;
    if (n >= NN) return;
    int s0 = padded ? (n << 6) : rowst[n];
    int c  = padded ? min(cnt[n], PSTR) : (rowst[n + 1] - rowst[n]);
    for (int s = sub; s < c; s += 16) {
        float4 p = pack[s0 + s];
        int src = __float_as_int(p.w);
        p.x *= dinv[src];
        p.y *= dinv[NN + src];
        p.z *= dinv[2 * NN + src];
        pack[s0 + s] = p;
    }
}

// ---------------- aggregation v3: FOUR nodes per wave (16 lanes each, 4 features/lane) ----
// 8-deep batch x 4 nodes = 32 rows in flight per wave (2x R18). Lane owns features
// 4*sub..4*sub+3 via one uint2 (8B) load per gathered row.
__global__ __launch_bounds__(256) void agg_kernel(const __half* __restrict__ h16,
                                                  const float4* __restrict__ pack,
                                                  const int* __restrict__ rowst,
                                                  const int* __restrict__ cnt,
                                                  const float* __restrict__ dinv,
                                                  __half* __restrict__ agg16,
                                                  int padded) {
    int wid  = (blockIdx.x * 256 + threadIdx.x) >> 6;
    int lane = threadIdx.x & 63;
    int q    = lane >> 4;        // quarter-wave: node select
    int sub  = lane & 15;        // feature group (4 features)
    int n = wid * 4 + q;
    if (n >= NN) return;
    float d0 = dinv[n], d1 = dinv[NN + n], d2 = dinv[2 * NN + n];
    uint2 hsu = *(const uint2*)&h16[((size_t)n << 6) + 4 * sub];
    float2 hA = __half22float2(*(__half2*)&hsu.x);
    float2 hB = __half22float2(*(__half2*)&hsu.y);
    float a0x = hA.x * d0, a0y = hA.y * d0, a0z = hB.x * d0, a0w = hB.y * d0;
    float a1x = hA.x * d1, a1y = hA.y * d1, a1z = hB.x * d1, a1w = hB.y * d1;
    float a2x = hA.x * d2, a2y = hA.y * d2, a2z = hB.x * d2, a2w = hB.y * d2;
    int s0 = padded ? (n << 6) : rowst[n];
    int s1 = s0 + (padded ? min(cnt[n], PSTR) : (rowst[n + 1] - rowst[n]));
    for (int s = s0; s < s1; s += 8) {
        float4 p[8];
#pragma unroll
        for (int u = 0; u < 8; ++u) {
            int idx = s + u;
            p[u] = pack[(idx < s1) ? idx : s0];
        }
        uint2 hv[8];
#pragma unroll
        for (int u = 0; u < 8; ++u)
            hv[u] = *(const uint2*)&h16[((size_t)__float_as_int(p[u].w) << 6) + 4 * sub];
#pragma unroll
        for (int u = 0; u < 8; ++u) {
            float m = (s + u < s1) ? 1.f : 0.f;
            float2 fA = __half22float2(*(__half2*)&hv[u].x);
            float2 fB = __half22float2(*(__half2*)&hv[u].y);
            fA.x *= m; fA.y *= m; fB.x *= m; fB.y *= m;
            a0x = fmaf(fA.x, p[u].x, a0x); a0y = fmaf(fA.y, p[u].x, a0y);
            a0z = fmaf(fB.x, p[u].x, a0z); a0w = fmaf(fB.y, p[u].x, a0w);
            a1x = fmaf(fA.x, p[u].y, a1x); a1y = fmaf(fA.y, p[u].y, a1y);
            a1z = fmaf(fB.x, p[u].y, a1z); a1w = fmaf(fB.y, p[u].y, a1w);
            a2x = fmaf(fA.x, p[u].z, a2x); a2y = fmaf(fA.y, p[u].z, a2y);
            a2z = fmaf(fB.x, p[u].z, a2z); a2w = fmaf(fB.y, p[u].z, a2w);
        }
    }
    size_t base = (size_t)n * 192 + 4 * sub;
    __half2 q0a = __floats2half2_rn(a0x * d0, a0y * d0);
    __half2 q0b = __floats2half2_rn(a0z * d0, a0w * d0);
    __half2 q1a = __floats2half2_rn(a1x * d1, a1y * d1);
    __half2 q1b = __floats2half2_rn(a1z * d1, a1w * d1);
    __half2 q2a = __floats2half2_rn(a2x * d2, a2y * d2);
    __half2 q2b = __floats2half2_rn(a2z * d2, a2w * d2);
    uint2 o0 = make_uint2(*(unsigned int*)&q0a, *(unsigned int*)&q0b);
    uint2 o1 = make_uint2(*(unsigned int*)&q1a, *(unsigned int*)&q1b);
    uint2 o2 = make_uint2(*(unsigned int*)&q2a, *(unsigned int*)&q2b);
    *(uint2*)&agg16[base]       = o0;
    *(uint2*)&agg16[base + 64]  = o1;
    *(uint2*)&agg16[base + 128] = o2;
}

// ---------------- GEMM v3: fp16-pair LDS tiles + v_dot2_f32_f16 inner loop ----------------
__global__ __launch_bounds__(256) void gemm_kernel(const __half* __restrict__ agg16,
                                                   const unsigned int* __restrict__ w16p,
                                                   const float* __restrict__ convb,
                                                   float* __restrict__ h,
                                                   __half* __restrict__ h16,
                                                   int layer, int dorelu, int writeshadow) {
    __shared__ unsigned int anp[32 * 68];   // [kk][r] pad 68
    __shared__ unsigned int wp[32 * 68];    // [kk][c] pad 68
    int t = threadIdx.x;
    int n0 = blockIdx.x * 64;
    const unsigned int* Wp = w16p + (size_t)layer * 96 * 64;
    const float* B = convb + (size_t)layer * 192;
    int nb = t >> 4, cb = t & 15;
    float acc[4][4] = {{0.f}};

    unsigned int fa[8], fw[8];
#pragma unroll
    for (int rep = 0; rep < 8; ++rep) {
        int flat = rep * 256 + t;
        int r = flat >> 5, kk = flat & 31;
        int n = n0 + r;
        fa[rep] = (n < NN) ? *(const unsigned int*)&agg16[(size_t)n * 192 + kk * 2] : 0u;
        int kg = flat >> 6, c = flat & 63;
        fw[rep] = Wp[(size_t)kg * 64 + c];
    }

    for (int kc = 0; kc < 3; ++kc) {
        __syncthreads();
#pragma unroll
        for (int rep = 0; rep < 8; ++rep) {
            int flat = rep * 256 + t;
            int r = flat >> 5, kk = flat & 31;
            anp[kk * 68 + r] = fa[rep];            // transposed store
            int kg = flat >> 6, c = flat & 63;
            wp[(kg & 31) * 68 + c] = fw[rep];
        }
        __syncthreads();
        if (kc < 2) {
#pragma unroll
            for (int rep = 0; rep < 8; ++rep) {
                int flat = rep * 256 + t;
                int r = flat >> 5, kk = flat & 31;
                int n = n0 + r;
                fa[rep] = (n < NN) ? *(const unsigned int*)&agg16[(size_t)n * 192 + (kc + 1) * 64 + kk * 2] : 0u;
                int kg = flat >> 6, c = flat & 63;
                fw[rep] = Wp[((size_t)(kc + 1) * 32 + kg) * 64 + c];
            }
        }
#pragma unroll 8
        for (int kk = 0; kk < 32; ++kk) {
            uint4 av = *(const uint4*)&anp[kk * 68 + nb * 4];
            uint4 wv = *(const uint4*)&wp[kk * 68 + cb * 4];
            const unsigned int avr[4] = { av.x, av.y, av.z, av.w };
            const unsigned int wvc[4] = { wv.x, wv.y, wv.z, wv.w };
#pragma unroll
            for (int r = 0; r < 4; ++r) {
#pragma unroll
                for (int c = 0; c < 4; ++c)
                    acc[r][c] = dot2acc(avr[r], wvc[c], acc[r][c]);
            }
        }
    }

    int col0 = cb * 4;
    float bs[4];
#pragma unroll
    for (int c = 0; c < 4; ++c) {
        int col = col0 + c;
        bs[c] = B[col] + B[64 + col] + B[128 + col];
    }
#pragma unroll
    for (int r = 0; r < 4; ++r) {
        int n = n0 + nb * 4 + r;
        if (n < NN) {
            float4 hv = *(const float4*)&h[(size_t)n * 64 + col0];
            float v0 = acc[r][0] + bs[0];
            float v1 = acc[r][1] + bs[1];
            float v2 = acc[r][2] + bs[2];
            float v3 = acc[r][3] + bs[3];
            if (dorelu) {
                v0 = fmaxf(v0, 0.f); v1 = fmaxf(v1, 0.f);
                v2 = fmaxf(v2, 0.f); v3 = fmaxf(v3, 0.f);
            }
            float4 o;
            o.x = v0 + hv.x; o.y = v1 + hv.y; o.z = v2 + hv.z; o.w = v3 + hv.w;
            *(float4*)&h[(size_t)n * 64 + col0] = o;
            if (writeshadow) {
                union { __half hh[4]; unsigned long long u; } pk;
                pk.hh[0] = __float2half(o.x);
                pk.hh[1] = __float2half(o.y);
                pk.hh[2] = __float2half(o.z);
                pk.hh[3] = __float2half(o.w);
                *(unsigned long long*)&h16[(size_t)n * 64 + col0] = pk.u;
            }
        }
    }
}

// ---------------- graph start offsets via binary search (batch is sorted) ----------------
__global__ __launch_bounds__(256) void gstart_kernel(const int* __restrict__ batch,
                                                     int* __restrict__ gstart) {
    int g = blockIdx.x * 256 + threadIdx.x;
    if (g > GG) return;
    int lo = 0, hi = NN;
    while (lo < hi) {
        int mid = (lo + hi) >> 1;
        if (batch[mid] < g) lo = mid + 1; else hi = mid;
    }
    gstart[g] = lo;
}

// ---------------- mean pool: one block (4 waves) per graph ----------------
__global__ __launch_bounds__(256) void pool_kernel(const float* __restrict__ h,
                                                   const int* __restrict__ gstart,
                                                   float* __restrict__ hg) {
    __shared__ float red[3][64];
    int g = blockIdx.x;
    int w = threadIdx.x >> 6, lane = threadIdx.x & 63;
    int s = gstart[g], e = gstart[g + 1];
    float sum = 0.f;
    for (int n = s + w; n < e; n += 4) sum += h[(size_t)n * 64 + lane];
    if (w) red[w - 1][lane] = sum;
    __syncthreads();
    if (w == 0) {
        sum += red[0][lane] + red[1][lane] + red[2][lane];
        int c = e - s;
        hg[(size_t)g * 64 + lane] = sum / (float)(c > 0 ? c : 1);
    }
}

// ---------------- fc: 3 stacked linears, one wave per graph ----------------
__global__ __launch_bounds__(256) void fc_kernel(const float* __restrict__ hg,
                                                 const float* __restrict__ W1, const float* __restrict__ b1,
                                                 const float* __restrict__ W2, const float* __restrict__ b2,
                                                 const float* __restrict__ W3, const float* __restrict__ b3,
                                                 float* __restrict__ out) {
    int g = (blockIdx.x * 256 + threadIdx.x) >> 6;
    int lane = threadIdx.x & 63;
    if (g >= GG) return;
    float x = hg[(size_t)g * 64 + lane];
    float t1 = b1[lane];
    for (int i = 0; i < 64; ++i) t1 = fmaf(__shfl(x, i, 64), W1[i * 64 + lane], t1);
    float t2 = b2[lane];
    for (int i = 0; i < 64; ++i) t2 = fmaf(__shfl(t1, i, 64), W2[i * 64 + lane], t2);
    float p = t2 * W3[lane];
    for (int off = 32; off > 0; off >>= 1) p += __shfl_down(p, off, 64);
    if (lane == 0) out[g] = p + b3[0];
}

extern "C" void kernel_launch(void* const* d_in, const int* in_sizes, int n_in,
                              void* d_out, int out_size, void* d_ws, size_t ws_size,
                              hipStream_t stream) {
    const int*   x_atom = (const int*)d_in[0];
    const int*   ei     = (const int*)d_in[1];
    const float* ea     = (const float*)d_in[2];
    const int*   batch  = (const int*)d_in[3];
    const float* emb    = (const float*)d_in[4];
    const float* convW  = (const float*)d_in[5];
    const float* convb  = (const float*)d_in[6];
    const float* W1 = (const float*)d_in[7];  const float* b1 = (const float*)d_in[8];
    const float* W2 = (const float*)d_in[9];  const float* b2 = (const float*)d_in[10];
    const float* W3 = (const float*)d_in[11]; const float* b3 = (const float*)d_in[12];
    float* out = (float*)d_out;

    char* p = (char*)d_ws;
    size_t used = 0;
    auto alloc = [&](size_t bytes) -> void* {
        void* r = (void*)p;
        size_t rb = (bytes + 255) & ~(size_t)255;
        p += rb; used += rb;
        return r;
    };
    float*  h     = (float*)alloc((size_t)NN * 64 * 4);       // 25.6 MB
    __half* h16   = (__half*)alloc((size_t)NN * 64 * 2);      // 12.8 MB (gather shadow)
    __half* agg16 = (__half*)alloc((size_t)NN * 192 * 2);     // 38.4 MB (fp16 intermediate)
    unsigned int* w16p = (unsigned int*)alloc((size_t)LL * 96 * 64 * 4);  // 74KB fp16 W pairs
    float*  dinv  = (float*)alloc((size_t)3 * NN * 4);        // 1.2 MB
    int*    hist  = (int*)alloc((size_t)NN * 4);
    int*    rowst = (int*)alloc((size_t)(NN + 1) * 4);
    int*    fill  = (int*)alloc((size_t)NN * 4);
    int*    bsum  = (int*)alloc(128 * 4);
    int*    boff  = (int*)alloc(128 * 4);
    int*    gstart= (int*)alloc((size_t)(GG + 1) * 4);
    float*  hg    = (float*)alloc((size_t)GG * 64 * 4);
    // pack last: padded (102.4 MB) if workspace allows, else compact (19.2 MB, +8 slot margin)
    size_t padded_pack  = (size_t)NN * PSTR * 16;
    size_t compact_pack = (size_t)(EE + 8) * 16;
    int padded = (ws_size >= used + padded_pack) ? 1 : 0;
    float4* pack = (float4*)alloc(padded ? padded_pack : compact_pack);

    // ---- encoder + W conversion + CSR build ----
    enc_kernel<<<(NN * 64) / 256, 256, 0, stream>>>(x_atom, emb, h, h16);
    wcvt_kernel<<<(LL * 96 * 64 + 255) / 256, 256, 0, stream>>>(convW, w16p);
    init_kernel<<<(NN + 255) / 256, 256, 0, stream>>>(hist, fill);
    if (!padded) {
        hist_kernel<<<(EE + 255) / 256, 256, 0, stream>>>(ei, hist);
        scan1_kernel<<<SCAN_NB, 256, 0, stream>>>(hist, bsum);
        scan2_kernel<<<1, 64, 0, stream>>>(bsum, boff, rowst);
        scan3_kernel<<<SCAN_NB, 256, 0, stream>>>(hist, boff, rowst);
    }
    fill_kernel<<<FILL_NB, 256, 0, stream>>>(ei, ea, rowst, fill, pack, padded);
    degdinv_kernel<<<(NN * 16 + 255) / 256, 256, 0, stream>>>(pack, rowst, fill, dinv, padded);
    normpack_kernel<<<(NN * 16 + 255) / 256, 256, 0, stream>>>(dinv, rowst, fill, pack, padded);
    gstart_kernel<<<(GG + 1 + 255) / 256, 256, 0, stream>>>(batch, gstart);

    // ---- 3 GCN layers: aggregate-then-GEMM (linearity refactor) ----
    const int aggblocks = (NN + 15) / 16;   // 4 nodes/wave, 4 waves/block
    for (int layer = 0; layer < LL; ++layer) {
        agg_kernel<<<aggblocks, 256, 0, stream>>>(h16, pack, rowst, fill, dinv, agg16, padded);
        gemm_kernel<<<(NN + 63) / 64, 256, 0, stream>>>(agg16, w16p, convb, h, h16, layer,
                                                        (layer < LL - 1) ? 1 : 0,
                                                        (layer < LL - 1) ? 1 : 0);
    }

    // ---- pool + fc ----
    pool_kernel<<<GG, 256, 0, stream>>>(h, gstart, hg);
    fc_kernel<<<GG / 4, 256, 0, stream>>>(hg, W1, b1, W2, b2, W3, b3, out);
}